// Round 4
// baseline (482.114 us; speedup 1.0000x reference)
//
#include <hip/hip_runtime.h>
#include <hip/hip_fp16.h>
#include <hip/hip_cooperative_groups.h>

namespace cg = cooperative_groups;

#define N_NODES 50000
#define N_EDGES 800000
#define IN_F 128
#define HID 128
#define NCLS 47
#define H2S 48          // padded H2 row stride (halfs)
#define W2C 64          // padded W2 col count (fp16 transposed)
#define NCH 196         // scan chunks (256 nodes each)
#define NB 128          // edge chunks per side
#define CHUNK 6250      // edges per chunk (NB*CHUNK == N_EDGES)
#define PDW 12500       // dwords per full histogram (u8 x 4 nodes) = 50 KB LDS
#define G1ROWS 256      // rows per gemm1 job (8 waves x 32 rows)
#define G2ROWS 256      // rows per gemm2 job (8 waves x 32 rows)
#define NTHR 512
#define MAXG 512

// u8 packing safety: per-chunk per-node counts <= ~8 and total degrees
// <= ~60 — all << 255, so packed-u8 dwords add carry-free.

typedef _Float16 f16x8 __attribute__((ext_vector_type(8)));
typedef float f32x4 __attribute__((ext_vector_type(4)));

struct __align__(8)  h2x2 { __half2 a, b; };
struct __align__(16) h2x4 { __half2 a, b, c, d; };

// ---------------------------------------------------------------------------
// ONE cooperative kernel, 7 phases separated by grid.sync():
//   A: hist (256 jobs) + weight fp16-hi/lo prep (48 jobs)
//   B: gemm1 MFMA (196 jobs) + reduce/chunk-scan (25 jobs)
//   C: offsets scan (98 jobs)    D: CSR fill (128 jobs)
//   E: gather1 (row-stride)      F: gemm2 MFMA (196 jobs)
//   G: gather2 (row-stride)
// Tests the launch-overhead hypothesis: 8 dispatches -> 1.
__global__ __launch_bounds__(NTHR, 4) void mega_kernel(
    const float* __restrict__ X, const int* __restrict__ ei,
    const float* __restrict__ W1, const float* __restrict__ b1,
    const float* __restrict__ W2, const float* __restrict__ b2,
    float* __restrict__ out,
    float* __restrict__ norm_src, float* __restrict__ norm_dst,
    int* __restrict__ cnt_in, int* __restrict__ offsets,
    int* __restrict__ csr_src, int* __restrict__ chunk_sums,
    __half* __restrict__ W1Th, __half* __restrict__ W1Tl,
    __half* __restrict__ W2Th, __half* __restrict__ W2Tl,
    __half* __restrict__ H1h, __half* __restrict__ Hrelu16,
    __half* __restrict__ H2h,
    unsigned int* __restrict__ Pdst, unsigned int* __restrict__ Psrc)
{
    cg::grid_group grid = cg::this_grid();
    __shared__ __align__(16) unsigned int lds[PDW];   // 50 KB arena, all phases
    const int t = threadIdx.x;
    const int G = gridDim.x;
    const int lane = t & 63;
    const int* srcp = ei;
    const int* dstp = ei + N_EDGES;

    // ---------------- phase A: hist + prep ----------------
    for (int job = blockIdx.x; job < 2 * NB + 48; job += G) {
        if (job < 2 * NB) {
            const bool is_src = job >= NB;
            const int chunk = job & (NB - 1);
            const int* ids = is_src ? srcp : dstp;
            uint2* h2 = (uint2*)lds;
            for (int j = t; j < PDW / 2; j += NTHR) h2[j] = make_uint2(0u, 0u);
            __syncthreads();
            const int e0 = chunk * CHUNK;
            const int2* e2p = (const int2*)(ids + e0);   // 8B-aligned
            for (int k = t; k < CHUNK / 2; k += NTHR) {
                int2 v2 = e2p[k];
                atomicAdd(&lds[v2.x >> 2], 1u << ((v2.x & 3) * 8));
                atomicAdd(&lds[v2.y >> 2], 1u << ((v2.y & 3) * 8));
            }
            __syncthreads();
            unsigned int* P = (is_src ? Psrc : Pdst) + (size_t)chunk * PDW;
            uint2* P2 = (uint2*)P;
            for (int j = t; j < PDW / 2; j += NTHR) P2[j] = h2[j];
            __syncthreads();
        } else {
            const int pj = job - 2 * NB;
            if (pj < 32) {
                const int i0 = pj * 512;                  // W1: 32 x 512 = 16384
                for (int i2 = i0 + t; i2 < i0 + 512; i2 += NTHR) {
                    int cc = i2 >> 7, k = i2 & 127;
                    float w = W1[k * HID + cc];
                    __half hv = __float2half_rn(w);
                    W1Th[i2] = hv;
                    W1Tl[i2] = __float2half_rn(w - __half2float(hv));
                }
            } else {
                const int i0 = (pj - 32) * 512;           // W2: 16 x 512 = 8192
                for (int i2 = i0 + t; i2 < i0 + 512; i2 += NTHR) {
                    int cc = i2 >> 7, k = i2 & 127;
                    float w = (cc < NCLS) ? W2[k * NCLS + cc] : 0.f;
                    __half hv = __float2half_rn(w);
                    W2Th[i2] = hv;
                    W2Tl[i2] = __float2half_rn(w - __half2float(hv));
                }
            }
        }
    }
    grid.sync();

    // ---------------- phase B: gemm1 + reduce ----------------
    for (int job = blockIdx.x; job < 221; job += G) {
        if (job < 196) {
            // gemm1: MFMA 16x16x32_f16, 256 rows/job, 8 waves.
            // A frag: row=lane&15, k=8*(lane>>4)+j; C: col=lane&15, row=4*(lane>>4)+reg
            const int wv = t >> 6;
            const int r16 = lane & 15;
            const int kg = lane >> 4;
            const int row0 = job * G1ROWS + wv * 32;
            f32x4 acc[2][8] = {};
#pragma unroll
            for (int s = 0; s < 4; ++s) {
                const int k0 = 32 * s + 8 * kg;
                f16x8 ah[2], al[2];
#pragma unroll
                for (int rt = 0; rt < 2; ++rt) {
                    int row = row0 + rt * 16 + r16;
                    int rc = row < N_NODES ? row : N_NODES - 1;
                    const float4 x0 = *(const float4*)&X[(size_t)rc * IN_F + k0];
                    const float4 x1 = *(const float4*)&X[(size_t)rc * IN_F + k0 + 4];
                    const float xv[8] = {x0.x, x0.y, x0.z, x0.w,
                                         x1.x, x1.y, x1.z, x1.w};
#pragma unroll
                    for (int j = 0; j < 8; ++j) {
                        _Float16 hv = (_Float16)xv[j];
                        ah[rt][j] = hv;
                        al[rt][j] = (_Float16)(xv[j] - (float)hv);
                    }
                }
#pragma unroll
                for (int tt = 0; tt < 8; ++tt) {
                    const f16x8 bh = *(const f16x8*)&W1Th[(16 * tt + r16) * IN_F + k0];
                    const f16x8 bl = *(const f16x8*)&W1Tl[(16 * tt + r16) * IN_F + k0];
#pragma unroll
                    for (int rt = 0; rt < 2; ++rt) {
                        acc[rt][tt] = __builtin_amdgcn_mfma_f32_16x16x32_f16(
                            ah[rt], bh, acc[rt][tt], 0, 0, 0);
                        acc[rt][tt] = __builtin_amdgcn_mfma_f32_16x16x32_f16(
                            al[rt], bh, acc[rt][tt], 0, 0, 0);
                        acc[rt][tt] = __builtin_amdgcn_mfma_f32_16x16x32_f16(
                            ah[rt], bl, acc[rt][tt], 0, 0, 0);
                    }
                }
            }
#pragma unroll
            for (int rt = 0; rt < 2; ++rt)
#pragma unroll
                for (int j = 0; j < 4; ++j) {
                    const int row = row0 + rt * 16 + 4 * kg + j;
                    if (row < N_NODES) {
#pragma unroll
                        for (int tt = 0; tt < 8; ++tt)
                            H1h[(size_t)row * HID + 16 * tt + r16] =
                                __float2half_rn(acc[rt][tt][j]);
                    }
                }
        } else {
            // reduce: 2 virtual 256-thread blocks per real block
            int* sm = (int*)lds;
            const int v = 2 * (job - 196) + (t >> 8);    // virtual block 0..49
            const int tl = t & 255;
            const int j = v * 256 + tl;
            int tot = 0;
            if (j < PDW) {
                unsigned int run = 0;
#pragma unroll 8
                for (int bb = 0; bb < NB; ++bb) {
                    unsigned int vv = Pdst[(size_t)bb * PDW + j];
                    Pdst[(size_t)bb * PDW + j] = run;    // exclusive prefix (u8 packed)
                    run += vv;
                }
                int n0 = run & 0xff, n1 = (run >> 8) & 0xff;
                int n2 = (run >> 16) & 0xff, n3 = (run >> 24) & 0xff;
                *(int4*)&cnt_in[4 * j] = make_int4(n0, n1, n2, n3);
                *(float4*)&norm_dst[4 * j] = make_float4(
                    rsqrtf(fmaxf((float)n0, 1.0f)), rsqrtf(fmaxf((float)n1, 1.0f)),
                    rsqrtf(fmaxf((float)n2, 1.0f)), rsqrtf(fmaxf((float)n3, 1.0f)));
                tot = n0 + n1 + n2 + n3;
                unsigned int rs = 0;
#pragma unroll 8
                for (int bb = 0; bb < NB; ++bb) rs += Psrc[(size_t)bb * PDW + j];
                int s0 = rs & 0xff, s1 = (rs >> 8) & 0xff;
                int s2 = (rs >> 16) & 0xff, s3 = (rs >> 24) & 0xff;
                *(float4*)&norm_src[4 * j] = make_float4(
                    rsqrtf(fmaxf((float)s0, 1.0f)), rsqrtf(fmaxf((float)s1, 1.0f)),
                    rsqrtf(fmaxf((float)s2, 1.0f)), rsqrtf(fmaxf((float)s3, 1.0f)));
            }
            sm[t] = tot;
            __syncthreads();
            for (int off = 32; off > 0; off >>= 1) {
                if ((t & 63) < off) sm[t] += sm[t + off];
                __syncthreads();
            }
            if ((t & 63) == 0) {
                int ci = v * 4 + (tl >> 6);
                if (ci < NCH) chunk_sums[ci] = sm[t];
            }
            __syncthreads();
        }
    }
    grid.sync();

    // ---------------- phase C: offsets scan ----------------
    for (int job = blockIdx.x; job < 98; job += G) {
        int* smc = (int*)lds;            // [0..255]  chunk prefix
        int* smn = (int*)lds + 256;      // [256..767] two node scans
        if (t < 256) smc[t] = (t < NCH) ? chunk_sums[t] : 0;
        __syncthreads();
        for (int off = 1; off < 256; off <<= 1) {
            int u = 0;
            if (t < 256 && t >= off) u = smc[t - off];
            __syncthreads();
            if (t < 256) smc[t] += u;
            __syncthreads();
        }
        const int v = 2 * job + (t >> 8);    // virtual 256-node block 0..195
        const int tl = t & 255;
        const int basev = (v == 0) ? 0 : smc[v - 1];
        const int idx = v * 256 + tl;
        int c = (idx < N_NODES) ? cnt_in[idx] : 0;
        smn[t] = c;
        __syncthreads();
        for (int off = 1; off < 256; off <<= 1) {
            int u = (tl >= off) ? smn[t - off] : 0;
            __syncthreads();
            smn[t] += u;
            __syncthreads();
        }
        if (idx < N_NODES) offsets[idx] = basev + smn[t] - c;
        if (job == 0 && t == 0) offsets[N_NODES] = N_EDGES;
        __syncthreads();
    }
    grid.sync();

    // ---------------- phase D: CSR fill ----------------
    for (int chunk = blockIdx.x; chunk < NB; chunk += G) {
        uint2* c2 = (uint2*)lds;
        for (int j = t; j < PDW / 2; j += NTHR) c2[j] = make_uint2(0u, 0u);
        __syncthreads();
        const unsigned int* base = Pdst + (size_t)chunk * PDW;
        const int e0 = chunk * CHUNK;
        const int2* d2p = (const int2*)(dstp + e0);
        const int2* s2p = (const int2*)(srcp + e0);
        for (int k = t; k < CHUNK / 2; k += NTHR) {
            int2 d2 = d2p[k];
            int2 s2 = s2p[k];
            {
                const int d = d2.x;
                const int sh = (d & 3) * 8;
                const unsigned int bw = base[d >> 2];
                const int off = offsets[d];
                unsigned int old = atomicAdd(&lds[d >> 2], 1u << sh);
                csr_src[off + (int)((bw >> sh) & 0xffu) + (int)((old >> sh) & 0xffu)] = s2.x;
            }
            {
                const int d = d2.y;
                const int sh = (d & 3) * 8;
                const unsigned int bw = base[d >> 2];
                const int off = offsets[d];
                unsigned int old = atomicAdd(&lds[d >> 2], 1u << sh);
                csr_src[off + (int)((bw >> sh) & 0xffu) + (int)((old >> sh) & 0xffu)] = s2.y;
            }
        }
        __syncthreads();
    }
    grid.sync();

    // ---------------- phase E: gather1 ----------------
    {
        const int q = lane >> 4;              // edge slot 0..3
        const int fl = lane & 15;             // features 8*fl..8*fl+7
        for (int r0 = blockIdx.x * 8; r0 < N_NODES; r0 += G * 8) {
            const int row = r0 + (t >> 6);
            const int beg = offsets[row], end = offsets[row + 1];
            float a0 = 0.f, a1 = 0.f, a2 = 0.f, a3 = 0.f;
            float a4 = 0.f, a5 = 0.f, a6 = 0.f, a7 = 0.f;
            for (int base = beg; base < end; base += 64) {
                int idx = 0;
                float nsv = 0.f;
                if (base + lane < end) {
                    idx = csr_src[base + lane];
                    nsv = norm_src[idx];
                }
                const int cnt = min(end - base, 64);
                for (int j = 0; j < cnt; j += 16) {
                    int e0 = j + q, e1 = j + 4 + q, e2 = j + 8 + q, e3 = j + 12 + q;
                    int s0 = __shfl(idx, e0);  float n0 = __shfl(nsv, e0);
                    int s1 = __shfl(idx, e1);  float n1 = __shfl(nsv, e1);
                    int s2 = __shfl(idx, e2);  float n2 = __shfl(nsv, e2);
                    int s3 = __shfl(idx, e3);  float n3 = __shfl(nsv, e3);
                    h2x4 v0 = *(const h2x4*)&H1h[(size_t)s0 * HID + 8 * fl];
                    h2x4 v1 = *(const h2x4*)&H1h[(size_t)s1 * HID + 8 * fl];
                    h2x4 v2 = *(const h2x4*)&H1h[(size_t)s2 * HID + 8 * fl];
                    h2x4 v3 = *(const h2x4*)&H1h[(size_t)s3 * HID + 8 * fl];
                    float2 f;
                    f = __half22float2(v0.a); a0 = fmaf(f.x, n0, a0); a1 = fmaf(f.y, n0, a1);
                    f = __half22float2(v0.b); a2 = fmaf(f.x, n0, a2); a3 = fmaf(f.y, n0, a3);
                    f = __half22float2(v0.c); a4 = fmaf(f.x, n0, a4); a5 = fmaf(f.y, n0, a5);
                    f = __half22float2(v0.d); a6 = fmaf(f.x, n0, a6); a7 = fmaf(f.y, n0, a7);
                    f = __half22float2(v1.a); a0 = fmaf(f.x, n1, a0); a1 = fmaf(f.y, n1, a1);
                    f = __half22float2(v1.b); a2 = fmaf(f.x, n1, a2); a3 = fmaf(f.y, n1, a3);
                    f = __half22float2(v1.c); a4 = fmaf(f.x, n1, a4); a5 = fmaf(f.y, n1, a5);
                    f = __half22float2(v1.d); a6 = fmaf(f.x, n1, a6); a7 = fmaf(f.y, n1, a7);
                    f = __half22float2(v2.a); a0 = fmaf(f.x, n2, a0); a1 = fmaf(f.y, n2, a1);
                    f = __half22float2(v2.b); a2 = fmaf(f.x, n2, a2); a3 = fmaf(f.y, n2, a3);
                    f = __half22float2(v2.c); a4 = fmaf(f.x, n2, a4); a5 = fmaf(f.y, n2, a5);
                    f = __half22float2(v2.d); a6 = fmaf(f.x, n2, a6); a7 = fmaf(f.y, n2, a7);
                    f = __half22float2(v3.a); a0 = fmaf(f.x, n3, a0); a1 = fmaf(f.y, n3, a1);
                    f = __half22float2(v3.b); a2 = fmaf(f.x, n3, a2); a3 = fmaf(f.y, n3, a3);
                    f = __half22float2(v3.c); a4 = fmaf(f.x, n3, a4); a5 = fmaf(f.y, n3, a5);
                    f = __half22float2(v3.d); a6 = fmaf(f.x, n3, a6); a7 = fmaf(f.y, n3, a7);
                }
            }
            a0 += __shfl_xor(a0, 16); a1 += __shfl_xor(a1, 16);
            a2 += __shfl_xor(a2, 16); a3 += __shfl_xor(a3, 16);
            a4 += __shfl_xor(a4, 16); a5 += __shfl_xor(a5, 16);
            a6 += __shfl_xor(a6, 16); a7 += __shfl_xor(a7, 16);
            a0 += __shfl_xor(a0, 32); a1 += __shfl_xor(a1, 32);
            a2 += __shfl_xor(a2, 32); a3 += __shfl_xor(a3, 32);
            a4 += __shfl_xor(a4, 32); a5 += __shfl_xor(a5, 32);
            a6 += __shfl_xor(a6, 32); a7 += __shfl_xor(a7, 32);
            if (lane < 16) {
                float nd = norm_dst[row], ns = norm_src[row];
                float4 bA = *(const float4*)&b1[8 * fl];
                float4 bB = *(const float4*)&b1[8 * fl + 4];
                float o0 = fmaxf(fmaf(a0, nd, bA.x), 0.f) * ns;
                float o1 = fmaxf(fmaf(a1, nd, bA.y), 0.f) * ns;
                float o2 = fmaxf(fmaf(a2, nd, bA.z), 0.f) * ns;
                float o3 = fmaxf(fmaf(a3, nd, bA.w), 0.f) * ns;
                float o4 = fmaxf(fmaf(a4, nd, bB.x), 0.f) * ns;
                float o5 = fmaxf(fmaf(a5, nd, bB.y), 0.f) * ns;
                float o6 = fmaxf(fmaf(a6, nd, bB.z), 0.f) * ns;
                float o7 = fmaxf(fmaf(a7, nd, bB.w), 0.f) * ns;
                h2x4 p = {__floats2half2_rn(o0, o1), __floats2half2_rn(o2, o3),
                          __floats2half2_rn(o4, o5), __floats2half2_rn(o6, o7)};
                *(h2x4*)&Hrelu16[(size_t)row * HID + 8 * fl] = p;
            }
        }
    }
    grid.sync();

    // ---------------- phase F: gemm2 ----------------
    for (int job = blockIdx.x; job < 196; job += G) {
        const int wv = t >> 6;
        const int r16 = lane & 15;
        const int kg = lane >> 4;
        const int row0 = job * G2ROWS + wv * 32;
        f32x4 acc[2][3] = {};                 // 3 col tiles = 48 cols exactly
#pragma unroll
        for (int s = 0; s < 4; ++s) {
            const int k0 = 32 * s + 8 * kg;
            f16x8 a[2];
#pragma unroll
            for (int rt = 0; rt < 2; ++rt) {
                int row = row0 + rt * 16 + r16;
                int rc = row < N_NODES ? row : N_NODES - 1;
                a[rt] = *(const f16x8*)&Hrelu16[(size_t)rc * HID + k0];
            }
#pragma unroll
            for (int tt = 0; tt < 3; ++tt) {
                const f16x8 bh = *(const f16x8*)&W2Th[(16 * tt + r16) * HID + k0];
                const f16x8 bl = *(const f16x8*)&W2Tl[(16 * tt + r16) * HID + k0];
#pragma unroll
                for (int rt = 0; rt < 2; ++rt) {
                    acc[rt][tt] = __builtin_amdgcn_mfma_f32_16x16x32_f16(
                        a[rt], bh, acc[rt][tt], 0, 0, 0);
                    acc[rt][tt] = __builtin_amdgcn_mfma_f32_16x16x32_f16(
                        a[rt], bl, acc[rt][tt], 0, 0, 0);
                }
            }
        }
#pragma unroll
        for (int rt = 0; rt < 2; ++rt)
#pragma unroll
            for (int j = 0; j < 4; ++j) {
                const int row = row0 + rt * 16 + 4 * kg + j;
                if (row < N_NODES) {
#pragma unroll
                    for (int tt = 0; tt < 3; ++tt)
                        H2h[(size_t)row * H2S + 16 * tt + r16] =
                            __float2half_rn(acc[rt][tt][j]);
                }
            }
    }
    grid.sync();

    // ---------------- phase G: gather2 ----------------
    {
        const int cl = min(lane, H2S - 1);
        for (int r0 = blockIdx.x * 8; r0 < N_NODES; r0 += G * 8) {
            const int row = r0 + (t >> 6);
            const int beg = offsets[row], end = offsets[row + 1];
            float acc = 0.f;
            for (int base = beg; base < end; base += 64) {
                int idx = 0;
                float wv = 0.f;
                if (base + lane < end) {
                    idx = csr_src[base + lane];
                    wv = 1.f;
                }
                const int cnt = min(end - base, 64);
                for (int j = 0; j < cnt; j += 4) {
                    int s0 = __shfl(idx, j);     float w0 = __shfl(wv, j);
                    int s1 = __shfl(idx, j + 1); float w1 = __shfl(wv, j + 1);
                    int s2 = __shfl(idx, j + 2); float w2 = __shfl(wv, j + 2);
                    int s3 = __shfl(idx, j + 3); float w3 = __shfl(wv, j + 3);
                    float f0 = __half2float(H2h[(size_t)s0 * H2S + cl]);
                    float f1 = __half2float(H2h[(size_t)s1 * H2S + cl]);
                    float f2 = __half2float(H2h[(size_t)s2 * H2S + cl]);
                    float f3 = __half2float(H2h[(size_t)s3 * H2S + cl]);
                    acc = fmaf(f0, w0, acc);
                    acc = fmaf(f1, w1, acc);
                    acc = fmaf(f2, w2, acc);
                    acc = fmaf(f3, w3, acc);
                }
            }
            if (lane < NCLS) out[(size_t)row * NCLS + lane] = acc * norm_dst[row] + b2[lane];
        }
    }
}

// ---------------------------------------------------------------------------
extern "C" void kernel_launch(void* const* d_in, const int* in_sizes, int n_in,
                              void* d_out, int out_size, void* d_ws, size_t ws_size,
                              hipStream_t stream) {
    const float* X  = (const float*)d_in[0];
    const int*   ei = (const int*)d_in[1];
    const float* W1 = (const float*)d_in[2];
    const float* b1 = (const float*)d_in[3];
    const float* W2 = (const float*)d_in[4];
    const float* b2 = (const float*)d_in[5];
    float* out = (float*)d_out;

    char* w = (char*)d_ws;
    auto alloc = [&](size_t bytes) {
        char* p = w;
        w += (bytes + 255) & ~(size_t)255;
        return p;
    };
    float*  norm_src   = (float*)alloc(N_NODES * 4);
    float*  norm_dst   = (float*)alloc(N_NODES * 4);
    int*    cnt_in     = (int*)alloc(N_NODES * 4);
    int*    offsets    = (int*)alloc((N_NODES + 1) * 4);
    int*    csr_src    = (int*)alloc((size_t)N_EDGES * 4);
    int*    chunk_sums = (int*)alloc(NCH * 4);
    __half* W1Th       = (__half*)alloc((size_t)IN_F * HID * 2);
    __half* W1Tl       = (__half*)alloc((size_t)IN_F * HID * 2);
    __half* W2Th       = (__half*)alloc((size_t)W2C * HID * 2);
    __half* W2Tl       = (__half*)alloc((size_t)W2C * HID * 2);
    __half* H1h        = (__half*)alloc((size_t)N_NODES * HID * 2);   // 12.8 MB
    __half* Hrelu16    = (__half*)alloc((size_t)N_NODES * HID * 2);   // 12.8 MB
    __half* H2h        = (__half*)alloc((size_t)N_NODES * H2S * 2);   //  4.8 MB
    unsigned int* Pdst = (unsigned int*)alloc((size_t)NB * PDW * 4);  //  6.4 MB
    unsigned int* Psrc = (unsigned int*)alloc((size_t)NB * PDW * 4);  //  6.4 MB

    // co-residency-safe grid: query actual blocks/CU for this kernel
    int maxActive = 0;
    hipOccupancyMaxActiveBlocksPerMultiprocessor(&maxActive, mega_kernel, NTHR, 0);
    if (maxActive < 1) maxActive = 1;
    long long Gl = (long long)maxActive * 256;
    int G = (Gl > MAXG) ? MAXG : (int)Gl;

    void* args[] = {
        (void*)&X, (void*)&ei, (void*)&W1, (void*)&b1, (void*)&W2, (void*)&b2,
        (void*)&out, (void*)&norm_src, (void*)&norm_dst, (void*)&cnt_in,
        (void*)&offsets, (void*)&csr_src, (void*)&chunk_sums,
        (void*)&W1Th, (void*)&W1Tl, (void*)&W2Th, (void*)&W2Tl,
        (void*)&H1h, (void*)&Hrelu16, (void*)&H2h, (void*)&Pdst, (void*)&Psrc };
    hipLaunchCooperativeKernel((void*)mega_kernel, dim3(G), dim3(NTHR),
                               args, 0, stream);
}

// Round 5
// 268.056 us; speedup vs baseline: 1.7986x; 1.7986x over previous
//
#include <hip/hip_runtime.h>
#include <hip/hip_fp16.h>

#define N_NODES 50000
#define N_EDGES 800000
#define IN_F 128
#define HID 128
#define NCLS 47
#define H2S 48          // padded H2 row stride (halfs)
#define W2C 64          // padded W2 col count (fp16 transposed)
#define NCH 196         // node chunks (256 nodes each)
#define G1ROWS 256      // rows per gemm1 job (8 waves x 32 rows)
#define G2ROWS 128      // rows per gemm2 block (4 waves x 32 rows)
#define DEGB 128        // degree-count blocks
#define FILLB 256       // CSR-fill blocks

typedef _Float16 f16x8 __attribute__((ext_vector_type(8)));
typedef float f32x4 __attribute__((ext_vector_type(4)));

struct __align__(8)  h2x2 { __half2 a, b; };
struct __align__(16) h2x4 { __half2 a, b, c, d; };

// ---------------------------------------------------------------------------
// deg+prep: blocks [0,DEGB) count in/out degrees via global atomics (deg
// arrays zeroed by a preceding memsetAsync). Blocks [DEGB,DEGB+3) build the
// fp16 hi/lo transposed weight splits (consumed by LATER dispatches only).
__global__ __launch_bounds__(512) void deg_prep_kernel(const int* __restrict__ ei,
        int* __restrict__ deg_in, int* __restrict__ deg_out,
        const float* __restrict__ W1, const float* __restrict__ W2,
        __half* __restrict__ W1Th, __half* __restrict__ W1Tl,
        __half* __restrict__ W2Th, __half* __restrict__ W2Tl) {
    const int t = threadIdx.x;
    if (blockIdx.x < DEGB) {
        const int4* s4 = (const int4*)ei;                // 16B-aligned
        const int4* d4 = (const int4*)(ei + N_EDGES);    // 3.2MB offset, aligned
        for (int k = blockIdx.x * 512 + t; k < N_EDGES / 4; k += DEGB * 512) {
            int4 s = s4[k];
            int4 d = d4[k];
            atomicAdd(&deg_out[s.x], 1); atomicAdd(&deg_out[s.y], 1);
            atomicAdd(&deg_out[s.z], 1); atomicAdd(&deg_out[s.w], 1);
            atomicAdd(&deg_in[d.x], 1);  atomicAdd(&deg_in[d.y], 1);
            atomicAdd(&deg_in[d.z], 1);  atomicAdd(&deg_in[d.w], 1);
        }
    } else {
        const int pj = blockIdx.x - DEGB;
        if (pj < 2) {
            // W1 -> transposed, fp16 hi/lo: W1T*[c*IN_F + k]
            const int i0 = pj * 8192;
            for (int i2 = i0 + t; i2 < i0 + 8192; i2 += 512) {
                int cc = i2 >> 7, k = i2 & 127;
                float w = W1[k * HID + cc];
                __half hv = __float2half_rn(w);
                W1Th[i2] = hv;
                W1Tl[i2] = __float2half_rn(w - __half2float(hv));
            }
        } else {
            // W2 -> padded, transposed, fp16 hi/lo: W2T*[c*HID + k]
            for (int i2 = t; i2 < W2C * HID; i2 += 512) {
                int cc = i2 >> 7, k = i2 & 127;
                float w = (cc < NCLS) ? W2[k * NCLS + cc] : 0.f;
                __half hv = __float2half_rn(w);
                W2Th[i2] = hv;
                W2Tl[i2] = __float2half_rn(w - __half2float(hv));
            }
        }
    }
}

// chunksum+norms: per-256-node chunk sums of deg_in; rsqrt norms from degs.
__global__ __launch_bounds__(256) void chunksum_kernel(const int* __restrict__ deg_in,
        const int* __restrict__ deg_out, float* __restrict__ norm_src,
        float* __restrict__ norm_dst, int* __restrict__ chunk_sums) {
    __shared__ int sm[256];
    const int t = threadIdx.x;
    const int i = blockIdx.x * 256 + t;
    int c = 0;
    if (i < N_NODES) {
        c = deg_in[i];
        int o = deg_out[i];
        norm_dst[i] = rsqrtf(fmaxf((float)c, 1.0f));
        norm_src[i] = rsqrtf(fmaxf((float)o, 1.0f));
    }
    sm[t] = c;
    __syncthreads();
    for (int off = 128; off > 0; off >>= 1) {
        if (t < off) sm[t] += sm[t + off];
        __syncthreads();
    }
    if (t == 0) chunk_sums[blockIdx.x] = sm[0];
}

// offsets: each block recomputes the chunk base from chunk_sums then scans
// its 256 nodes; also seeds the atomic fill cursor with the offsets.
__global__ __launch_bounds__(256) void scan3_kernel(const int* __restrict__ deg_in,
                                                    const int* __restrict__ chunk_sums,
                                                    int* __restrict__ offsets,
                                                    int* __restrict__ cursor) {
    __shared__ int sm[256];
    const int t = threadIdx.x;
    int v = (t < NCH) ? chunk_sums[t] : 0;
    sm[t] = v;
    __syncthreads();
    for (int off = 1; off < 256; off <<= 1) {
        int u = (t >= off) ? sm[t - off] : 0;
        __syncthreads();
        sm[t] += u;
        __syncthreads();
    }
    const int basev = (blockIdx.x == 0) ? 0 : sm[blockIdx.x - 1];
    __syncthreads();
    const int idx = blockIdx.x * 256 + t;
    int c = (idx < N_NODES) ? deg_in[idx] : 0;
    sm[t] = c;
    __syncthreads();
    for (int off = 1; off < 256; off <<= 1) {
        int u = (t >= off) ? sm[t - off] : 0;
        __syncthreads();
        sm[t] += u;
        __syncthreads();
    }
    if (idx < N_NODES) {
        int o = basev + sm[t] - c;
        offsets[idx] = o;
        cursor[idx] = o;
    }
    if (blockIdx.x == 0 && t == 0) offsets[N_NODES] = N_EDGES;
}

// fill+gemm1: blocks [0,196) run gemm1 as MFMA with norm_src BAKED into H1h
// (norms ready since chunksum). Blocks [196,196+FILLB) scatter CSR slots via
// global atomic cursor — slot order within a row is arbitrary (sum-invariant).
__global__ __launch_bounds__(512) void fill_gemm1_kernel(const int* __restrict__ ei,
        int* __restrict__ cursor, int* __restrict__ csr_src,
        const float* __restrict__ X, const float* __restrict__ norm_src,
        const __half* __restrict__ W1Th, const __half* __restrict__ W1Tl,
        __half* __restrict__ H1h) {
    const int t = threadIdx.x;
    if (blockIdx.x >= 196) {
        const int b = blockIdx.x - 196;
        const int4* s4 = (const int4*)ei;
        const int4* d4 = (const int4*)(ei + N_EDGES);
        for (int k = b * 512 + t; k < N_EDGES / 4; k += FILLB * 512) {
            int4 s = s4[k];
            int4 d = d4[k];
            int o0 = atomicAdd(&cursor[d.x], 1);
            int o1 = atomicAdd(&cursor[d.y], 1);
            int o2 = atomicAdd(&cursor[d.z], 1);
            int o3 = atomicAdd(&cursor[d.w], 1);
            csr_src[o0] = s.x;
            csr_src[o1] = s.y;
            csr_src[o2] = s.z;
            csr_src[o3] = s.w;
        }
    } else {
        // ---- gemm1: MFMA 16x16x32_f16, 256 rows/block, 8 waves ----
        // A frag: row=lane&15, k=8*(lane>>4)+j; C: col=lane&15, row=4*(lane>>4)+reg
        const int lane = t & 63;
        const int wv = t >> 6;
        const int r16 = lane & 15;
        const int kg = lane >> 4;
        const int row0 = blockIdx.x * G1ROWS + wv * 32;
        f32x4 acc[2][8] = {};
#pragma unroll
        for (int s = 0; s < 4; ++s) {                // K steps of 32
            const int k0 = 32 * s + 8 * kg;
            f16x8 ah[2], al[2];
#pragma unroll
            for (int rt = 0; rt < 2; ++rt) {
                int row = row0 + rt * 16 + r16;
                int rc = row < N_NODES ? row : N_NODES - 1;
                const float4 x0 = *(const float4*)&X[(size_t)rc * IN_F + k0];
                const float4 x1 = *(const float4*)&X[(size_t)rc * IN_F + k0 + 4];
                const float xv[8] = {x0.x, x0.y, x0.z, x0.w,
                                     x1.x, x1.y, x1.z, x1.w};
#pragma unroll
                for (int j = 0; j < 8; ++j) {
                    _Float16 hv = (_Float16)xv[j];
                    ah[rt][j] = hv;
                    al[rt][j] = (_Float16)(xv[j] - (float)hv);
                }
            }
#pragma unroll
            for (int tt = 0; tt < 8; ++tt) {         // 8 col tiles of 16
                const f16x8 bh = *(const f16x8*)&W1Th[(16 * tt + r16) * IN_F + k0];
                const f16x8 bl = *(const f16x8*)&W1Tl[(16 * tt + r16) * IN_F + k0];
#pragma unroll
                for (int rt = 0; rt < 2; ++rt) {
                    acc[rt][tt] = __builtin_amdgcn_mfma_f32_16x16x32_f16(
                        ah[rt], bh, acc[rt][tt], 0, 0, 0);
                    acc[rt][tt] = __builtin_amdgcn_mfma_f32_16x16x32_f16(
                        al[rt], bh, acc[rt][tt], 0, 0, 0);
                    acc[rt][tt] = __builtin_amdgcn_mfma_f32_16x16x32_f16(
                        ah[rt], bl, acc[rt][tt], 0, 0, 0);
                }
            }
        }
#pragma unroll
        for (int rt = 0; rt < 2; ++rt)
#pragma unroll
            for (int j = 0; j < 4; ++j) {
                const int row = row0 + rt * 16 + 4 * kg + j;
                if (row < N_NODES) {
                    const float nsr = norm_src[row];     // bake d_out^-1/2
#pragma unroll
                    for (int tt = 0; tt < 8; ++tt)
                        H1h[(size_t)row * HID + 16 * tt + r16] =
                            __float2half_rn(acc[rt][tt][j] * nsr);
                }
            }
    }
}

// --- gather1: Hrelu16[row,:] = fp16(relu((sum H1h[s,:])*nd + b1)*ns) -------
// (norm_src already baked into H1h rows)
__global__ __launch_bounds__(256) void gather1_kernel(const __half* __restrict__ H1h,
        const int* __restrict__ offsets, const int* __restrict__ csr_src,
        const float* __restrict__ b1, const float* __restrict__ norm_src,
        const float* __restrict__ norm_dst, __half* __restrict__ Hrelu16) {
    const int lane = threadIdx.x & 63;
    const int q = lane >> 4;              // edge slot 0..3
    const int fl = lane & 15;             // features 8*fl .. 8*fl+7
    const int row = blockIdx.x * 4 + (threadIdx.x >> 6);
    const int beg = offsets[row], end = offsets[row + 1];
    float a0 = 0.f, a1 = 0.f, a2 = 0.f, a3 = 0.f;
    float a4 = 0.f, a5 = 0.f, a6 = 0.f, a7 = 0.f;
    for (int base = beg; base < end; base += 64) {
        int idx = 0;
        float wv = 0.f;
        if (base + lane < end) {
            idx = csr_src[base + lane];
            wv = 1.f;
        }
        const int cnt = min(end - base, 64);
        for (int j = 0; j < cnt; j += 16) {
            int e0 = j + q, e1 = j + 4 + q, e2 = j + 8 + q, e3 = j + 12 + q;
            int s0 = __shfl(idx, e0);  float n0 = __shfl(wv, e0);
            int s1 = __shfl(idx, e1);  float n1 = __shfl(wv, e1);
            int s2 = __shfl(idx, e2);  float n2 = __shfl(wv, e2);
            int s3 = __shfl(idx, e3);  float n3 = __shfl(wv, e3);
            h2x4 v0 = *(const h2x4*)&H1h[(size_t)s0 * HID + 8 * fl];
            h2x4 v1 = *(const h2x4*)&H1h[(size_t)s1 * HID + 8 * fl];
            h2x4 v2 = *(const h2x4*)&H1h[(size_t)s2 * HID + 8 * fl];
            h2x4 v3 = *(const h2x4*)&H1h[(size_t)s3 * HID + 8 * fl];
            float2 f;
            f = __half22float2(v0.a); a0 = fmaf(f.x, n0, a0); a1 = fmaf(f.y, n0, a1);
            f = __half22float2(v0.b); a2 = fmaf(f.x, n0, a2); a3 = fmaf(f.y, n0, a3);
            f = __half22float2(v0.c); a4 = fmaf(f.x, n0, a4); a5 = fmaf(f.y, n0, a5);
            f = __half22float2(v0.d); a6 = fmaf(f.x, n0, a6); a7 = fmaf(f.y, n0, a7);
            f = __half22float2(v1.a); a0 = fmaf(f.x, n1, a0); a1 = fmaf(f.y, n1, a1);
            f = __half22float2(v1.b); a2 = fmaf(f.x, n1, a2); a3 = fmaf(f.y, n1, a3);
            f = __half22float2(v1.c); a4 = fmaf(f.x, n1, a4); a5 = fmaf(f.y, n1, a5);
            f = __half22float2(v1.d); a6 = fmaf(f.x, n1, a6); a7 = fmaf(f.y, n1, a7);
            f = __half22float2(v2.a); a0 = fmaf(f.x, n2, a0); a1 = fmaf(f.y, n2, a1);
            f = __half22float2(v2.b); a2 = fmaf(f.x, n2, a2); a3 = fmaf(f.y, n2, a3);
            f = __half22float2(v2.c); a4 = fmaf(f.x, n2, a4); a5 = fmaf(f.y, n2, a5);
            f = __half22float2(v2.d); a6 = fmaf(f.x, n2, a6); a7 = fmaf(f.y, n2, a7);
            f = __half22float2(v3.a); a0 = fmaf(f.x, n3, a0); a1 = fmaf(f.y, n3, a1);
            f = __half22float2(v3.b); a2 = fmaf(f.x, n3, a2); a3 = fmaf(f.y, n3, a3);
            f = __half22float2(v3.c); a4 = fmaf(f.x, n3, a4); a5 = fmaf(f.y, n3, a5);
            f = __half22float2(v3.d); a6 = fmaf(f.x, n3, a6); a7 = fmaf(f.y, n3, a7);
        }
    }
    a0 += __shfl_xor(a0, 16); a1 += __shfl_xor(a1, 16);
    a2 += __shfl_xor(a2, 16); a3 += __shfl_xor(a3, 16);
    a4 += __shfl_xor(a4, 16); a5 += __shfl_xor(a5, 16);
    a6 += __shfl_xor(a6, 16); a7 += __shfl_xor(a7, 16);
    a0 += __shfl_xor(a0, 32); a1 += __shfl_xor(a1, 32);
    a2 += __shfl_xor(a2, 32); a3 += __shfl_xor(a3, 32);
    a4 += __shfl_xor(a4, 32); a5 += __shfl_xor(a5, 32);
    a6 += __shfl_xor(a6, 32); a7 += __shfl_xor(a7, 32);
    if (lane < 16) {
        float nd = norm_dst[row], ns = norm_src[row];
        float4 bA = *(const float4*)&b1[8 * fl];
        float4 bB = *(const float4*)&b1[8 * fl + 4];
        float o0 = fmaxf(fmaf(a0, nd, bA.x), 0.f) * ns;
        float o1 = fmaxf(fmaf(a1, nd, bA.y), 0.f) * ns;
        float o2 = fmaxf(fmaf(a2, nd, bA.z), 0.f) * ns;
        float o3 = fmaxf(fmaf(a3, nd, bA.w), 0.f) * ns;
        float o4 = fmaxf(fmaf(a4, nd, bB.x), 0.f) * ns;
        float o5 = fmaxf(fmaf(a5, nd, bB.y), 0.f) * ns;
        float o6 = fmaxf(fmaf(a6, nd, bB.z), 0.f) * ns;
        float o7 = fmaxf(fmaf(a7, nd, bB.w), 0.f) * ns;
        h2x4 p = {__floats2half2_rn(o0, o1), __floats2half2_rn(o2, o3),
                  __floats2half2_rn(o4, o5), __floats2half2_rn(o6, o7)};
        *(h2x4*)&Hrelu16[(size_t)row * HID + 8 * fl] = p;
    }
}

// --- gemm2: H2h[row, 0..47] = fp16( Hrelu16[row,:] @ W2 ), MFMA, no LDS ---
__global__ __launch_bounds__(256) void gemm2_kernel(const __half* __restrict__ Hrelu16,
                                                    const __half* __restrict__ W2Th,
                                                    const __half* __restrict__ W2Tl,
                                                    __half* __restrict__ H2h) {
    const int lane = threadIdx.x & 63;
    const int wv = threadIdx.x >> 6;
    const int r16 = lane & 15;
    const int kg = lane >> 4;
    const int row0 = blockIdx.x * G2ROWS + wv * 32;
    f32x4 acc[2][3] = {};                 // 3 col tiles = 48 cols exactly
#pragma unroll
    for (int s = 0; s < 4; ++s) {
        const int k0 = 32 * s + 8 * kg;
        f16x8 a[2];
#pragma unroll
        for (int rt = 0; rt < 2; ++rt) {
            int row = row0 + rt * 16 + r16;
            int rc = row < N_NODES ? row : N_NODES - 1;
            a[rt] = *(const f16x8*)&Hrelu16[(size_t)rc * HID + k0];
        }
#pragma unroll
        for (int tt = 0; tt < 3; ++tt) {
            const f16x8 bh = *(const f16x8*)&W2Th[(16 * tt + r16) * HID + k0];
            const f16x8 bl = *(const f16x8*)&W2Tl[(16 * tt + r16) * HID + k0];
#pragma unroll
            for (int rt = 0; rt < 2; ++rt) {
                acc[rt][tt] = __builtin_amdgcn_mfma_f32_16x16x32_f16(
                    a[rt], bh, acc[rt][tt], 0, 0, 0);
                acc[rt][tt] = __builtin_amdgcn_mfma_f32_16x16x32_f16(
                    a[rt], bl, acc[rt][tt], 0, 0, 0);
            }
        }
    }
#pragma unroll
    for (int rt = 0; rt < 2; ++rt)
#pragma unroll
        for (int j = 0; j < 4; ++j) {
            const int row = row0 + rt * 16 + 4 * kg + j;
            if (row < N_NODES) {
#pragma unroll
                for (int tt = 0; tt < 3; ++tt)
                    H2h[(size_t)row * H2S + 16 * tt + r16] =
                        __float2half_rn(acc[rt][tt][j]);
            }
        }
}

// --- gather2: out[row,c] = (sum H2h[s,c])*nd + b2[c]; weight-masked tail ---
__global__ __launch_bounds__(256) void gather2_kernel(const __half* __restrict__ H2h,
        const int* __restrict__ offsets, const int* __restrict__ csr_src,
        const float* __restrict__ b2, const float* __restrict__ norm_dst,
        float* __restrict__ out) {
    const int lane = threadIdx.x & 63;
    const int row = blockIdx.x * 4 + (threadIdx.x >> 6);
    const int beg = offsets[row], end = offsets[row + 1];
    const int cl = min(lane, H2S - 1);
    float acc = 0.f;
    for (int base = beg; base < end; base += 64) {
        int idx = 0;
        float wv = 0.f;
        if (base + lane < end) {
            idx = csr_src[base + lane];
            wv = 1.f;
        }
        const int cnt = min(end - base, 64);
        for (int j = 0; j < cnt; j += 4) {
            int s0 = __shfl(idx, j);     float w0 = __shfl(wv, j);
            int s1 = __shfl(idx, j + 1); float w1 = __shfl(wv, j + 1);
            int s2 = __shfl(idx, j + 2); float w2 = __shfl(wv, j + 2);
            int s3 = __shfl(idx, j + 3); float w3 = __shfl(wv, j + 3);
            float f0 = __half2float(H2h[(size_t)s0 * H2S + cl]);
            float f1 = __half2float(H2h[(size_t)s1 * H2S + cl]);
            float f2 = __half2float(H2h[(size_t)s2 * H2S + cl]);
            float f3 = __half2float(H2h[(size_t)s3 * H2S + cl]);
            acc = fmaf(f0, w0, acc);
            acc = fmaf(f1, w1, acc);
            acc = fmaf(f2, w2, acc);
            acc = fmaf(f3, w3, acc);
        }
    }
    if (lane < NCLS) out[(size_t)row * NCLS + lane] = acc * norm_dst[row] + b2[lane];
}

// ---------------------------------------------------------------------------
extern "C" void kernel_launch(void* const* d_in, const int* in_sizes, int n_in,
                              void* d_out, int out_size, void* d_ws, size_t ws_size,
                              hipStream_t stream) {
    const float* X  = (const float*)d_in[0];
    const int*   ei = (const int*)d_in[1];
    const float* W1 = (const float*)d_in[2];
    const float* b1 = (const float*)d_in[3];
    const float* W2 = (const float*)d_in[4];
    const float* b2 = (const float*)d_in[5];
    float* out = (float*)d_out;

    char* w = (char*)d_ws;
    auto alloc = [&](size_t bytes) {
        char* p = w;
        w += (bytes + 255) & ~(size_t)255;
        return p;
    };
    int*    deg        = (int*)alloc((size_t)2 * N_NODES * 4);   // deg_in|deg_out
    int*    deg_in     = deg;
    int*    deg_out    = deg + N_NODES;
    int*    cursor     = (int*)alloc(N_NODES * 4);
    float*  norm_src   = (float*)alloc(N_NODES * 4);
    float*  norm_dst   = (float*)alloc(N_NODES * 4);
    int*    offsets    = (int*)alloc((N_NODES + 1) * 4);
    int*    csr_src    = (int*)alloc((size_t)N_EDGES * 4);
    int*    chunk_sums = (int*)alloc(NCH * 4);
    __half* W1Th       = (__half*)alloc((size_t)IN_F * HID * 2);
    __half* W1Tl       = (__half*)alloc((size_t)IN_F * HID * 2);
    __half* W2Th       = (__half*)alloc((size_t)W2C * HID * 2);
    __half* W2Tl       = (__half*)alloc((size_t)W2C * HID * 2);
    __half* H1h        = (__half*)alloc((size_t)N_NODES * HID * 2);   // 12.8 MB
    __half* Hrelu16    = (__half*)alloc((size_t)N_NODES * HID * 2);   // 12.8 MB
    __half* H2h        = (__half*)alloc((size_t)N_NODES * H2S * 2);   //  4.8 MB

    const int g1_blocks = (N_NODES + G1ROWS - 1) / G1ROWS;            // 196
    const int g2_blocks = (N_NODES + G2ROWS - 1) / G2ROWS;            // 391

    hipMemsetAsync(deg, 0, (size_t)2 * N_NODES * 4, stream);
    deg_prep_kernel<<<DEGB + 3, 512, 0, stream>>>(ei, deg_in, deg_out, W1, W2,
                                                  W1Th, W1Tl, W2Th, W2Tl);
    chunksum_kernel<<<NCH, 256, 0, stream>>>(deg_in, deg_out, norm_src,
                                             norm_dst, chunk_sums);
    scan3_kernel<<<NCH, 256, 0, stream>>>(deg_in, chunk_sums, offsets, cursor);
    fill_gemm1_kernel<<<196 + FILLB, 512, 0, stream>>>(ei, cursor, csr_src,
                                                       X, norm_src,
                                                       W1Th, W1Tl, H1h);
    gather1_kernel<<<N_NODES / 4, 256, 0, stream>>>(H1h, offsets, csr_src, b1,
                                                    norm_src, norm_dst, Hrelu16);
    gemm2_kernel<<<g2_blocks, 256, 0, stream>>>(Hrelu16, W2Th, W2Tl, H2h);
    gather2_kernel<<<N_NODES / 4, 256, 0, stream>>>(H2h, offsets, csr_src, b2,
                                                    norm_dst, out);
}

// Round 6
// 221.468 us; speedup vs baseline: 2.1769x; 1.2104x over previous
//
#include <hip/hip_runtime.h>
#include <hip/hip_fp16.h>

#define N_NODES 50000
#define N_EDGES 800000
#define IN_F 128
#define HID 128
#define NCLS 47
#define H2S 48          // H2 row stride (halfs)
#define NB 128          // edge chunks per side
#define CHUNK 6250      // edges per chunk (NB*CHUNK == N_EDGES)
#define PDW 12500       // dwords per full histogram (u8 x 4 nodes) = 50 KB LDS
#define G1ROWS 256      // rows per gemm1 job (8 waves x 32 rows)
#define RSB 98          // reduce_scan blocks (co-resident, <= 256 CUs)
#define RSC 128         // j-columns per reduce_scan block (= 2 node chunks)

// u8 packing safety: per-chunk per-node counts <= ~8 and total degrees
// <= ~60 — all << 255, so packed-u8 dwords add carry-free.

typedef _Float16 f16x8 __attribute__((ext_vector_type(8)));
typedef float f32x4 __attribute__((ext_vector_type(4)));

struct __align__(8)  h2x2 { __half2 a, b; };
struct __align__(16) h2x4 { __half2 a, b, c, d; };

// ---------------------------------------------------------------------------
// prep: fp16 hi/lo transposed weight splits + sync-flag init (workspace is
// re-poisoned between iterations, so flags must be re-zeroed every launch).
__global__ __launch_bounds__(256) void prep_kernel(const float* __restrict__ W1,
                                                   const float* __restrict__ W2,
                                                   __half* __restrict__ W1Th,
                                                   __half* __restrict__ W1Tl,
                                                   __half* __restrict__ W2Th,
                                                   __half* __restrict__ W2Tl,
                                                   int* __restrict__ sync) {
    const int b = blockIdx.x, t = threadIdx.x;
    if (b < 32) {
        // W1 -> transposed, fp16 hi/lo: W1T*[c*IN_F + k]
        const int i0 = b * 512;
        for (int i2 = i0 + t; i2 < i0 + 512; i2 += 256) {
            int cc = i2 >> 7, k = i2 & 127;
            float w = W1[k * HID + cc];
            __half hv = __float2half_rn(w);
            W1Th[i2] = hv;
            W1Tl[i2] = __float2half_rn(w - __half2float(hv));
        }
    } else if (b < 48) {
        // W2 -> padded(64), transposed, fp16 hi/lo: W2T*[c*HID + k]
        const int i0 = (b - 32) * 512;                 // 16 x 512 = 8192
        for (int i2 = i0 + t; i2 < i0 + 512; i2 += 256) {
            int cc = i2 >> 7, k = i2 & 127;
            float w = (cc < NCLS) ? W2[k * NCLS + cc] : 0.f;
            __half hv = __float2half_rn(w);
            W2Th[i2] = hv;
            W2Tl[i2] = __float2half_rn(w - __half2float(hv));
        }
    } else {
        if (t < 2) sync[t] = 0;
    }
}

// ---------------------------------------------------------------------------
// hist+gemm1 mega: blocks [0,2NB) build one FULL-RANGE u8 histogram per
// (side, chunk) — every edge read once, all lanes active. Blocks [2NB,...)
// run gemm1 as MFMA (needs prep's W1T; overlaps hist).
__global__ __launch_bounds__(512) void hist_gemm1_kernel(const int* __restrict__ ei,
        unsigned int* __restrict__ Pdst, unsigned int* __restrict__ Psrc,
        const float* __restrict__ X, const __half* __restrict__ W1Th,
        const __half* __restrict__ W1Tl, __half* __restrict__ H1h) {
    __shared__ unsigned int h[PDW];              // 50 KB u8-packed counters
    const int t = threadIdx.x;
    if (blockIdx.x < 2 * NB) {
        const bool is_src = blockIdx.x >= NB;
        const int chunk = blockIdx.x & (NB - 1);
        const int* ids = is_src ? ei : ei + N_EDGES;
        uint2* h2 = (uint2*)h;
        for (int j = t; j < PDW / 2; j += 512) h2[j] = make_uint2(0u, 0u);
        __syncthreads();
        const int e0 = chunk * CHUNK;
        const int2* e2p = (const int2*)(ids + e0);   // 8B-aligned
        for (int k = t; k < CHUNK / 2; k += 512) {
            int2 v2 = e2p[k];
            atomicAdd(&h[v2.x >> 2], 1u << ((v2.x & 3) * 8));
            atomicAdd(&h[v2.y >> 2], 1u << ((v2.y & 3) * 8));
        }
        __syncthreads();
        unsigned int* P = (is_src ? Psrc : Pdst) + (size_t)chunk * PDW;
        uint2* P2 = (uint2*)P;
        for (int j = t; j < PDW / 2; j += 512) P2[j] = h2[j];
    } else {
        // ---- gemm1: MFMA 16x16x32_f16, 256 rows/block, 8 waves ----
        // A frag: row=lane&15, k=8*(lane>>4)+j; C: col=lane&15, row=4*(lane>>4)+reg
        const int lane = t & 63;
        const int wv = t >> 6;
        const int r16 = lane & 15;
        const int kg = lane >> 4;
        const int row0 = (blockIdx.x - 2 * NB) * G1ROWS + wv * 32;
        f32x4 acc[2][8] = {};
#pragma unroll
        for (int s = 0; s < 4; ++s) {                // K steps of 32
            const int k0 = 32 * s + 8 * kg;
            f16x8 ah[2], al[2];
#pragma unroll
            for (int rt = 0; rt < 2; ++rt) {
                int row = row0 + rt * 16 + r16;
                int rc = row < N_NODES ? row : N_NODES - 1;
                const float4 x0 = *(const float4*)&X[(size_t)rc * IN_F + k0];
                const float4 x1 = *(const float4*)&X[(size_t)rc * IN_F + k0 + 4];
                const float xv[8] = {x0.x, x0.y, x0.z, x0.w,
                                     x1.x, x1.y, x1.z, x1.w};
#pragma unroll
                for (int j = 0; j < 8; ++j) {
                    _Float16 hv = (_Float16)xv[j];
                    ah[rt][j] = hv;
                    al[rt][j] = (_Float16)(xv[j] - (float)hv);
                }
            }
#pragma unroll
            for (int tt = 0; tt < 8; ++tt) {         // 8 col tiles of 16
                const f16x8 bh = *(const f16x8*)&W1Th[(16 * tt + r16) * IN_F + k0];
                const f16x8 bl = *(const f16x8*)&W1Tl[(16 * tt + r16) * IN_F + k0];
#pragma unroll
                for (int rt = 0; rt < 2; ++rt) {
                    acc[rt][tt] = __builtin_amdgcn_mfma_f32_16x16x32_f16(
                        ah[rt], bh, acc[rt][tt], 0, 0, 0);
                    acc[rt][tt] = __builtin_amdgcn_mfma_f32_16x16x32_f16(
                        al[rt], bh, acc[rt][tt], 0, 0, 0);
                    acc[rt][tt] = __builtin_amdgcn_mfma_f32_16x16x32_f16(
                        ah[rt], bl, acc[rt][tt], 0, 0, 0);
                }
            }
        }
#pragma unroll
        for (int rt = 0; rt < 2; ++rt)
#pragma unroll
            for (int j = 0; j < 4; ++j) {
                const int row = row0 + rt * 16 + 4 * kg + j;
                if (row < N_NODES) {
#pragma unroll
                    for (int tt = 0; tt < 8; ++tt)
                        H1h[(size_t)row * HID + 16 * tt + r16] =
                            __float2half_rn(acc[rt][tt][j]);
                }
            }
    }
}

// ---------------------------------------------------------------------------
// reduce+scan fused (98 co-resident blocks, flag sync). Block b owns
// j-columns [b*128, b*128+128) == nodes [b*512, (b+1)*512) == chunks
// {2b, 2b+1}, so per-node counts stay in registers across phases.
// Cross-block data (chunk sums/bases, flags) moves ONLY via device atomics.
__global__ __launch_bounds__(256) void reduce_scan_kernel(
        unsigned int* __restrict__ Pdst, const unsigned int* __restrict__ Psrc,
        float* __restrict__ norm_src, float* __restrict__ norm_dst,
        int* __restrict__ offsets, int* __restrict__ chunk_sums,
        int* __restrict__ chunk_base, int* __restrict__ sync) {
    __shared__ int sm[256];
    const int t = threadIdx.x;
    const int b = blockIdx.x;
    const int j = b * RSC + t;                       // valid for t<RSC
    unsigned int run = 0;
    int n0 = 0, n1 = 0, n2 = 0, n3 = 0, tot = 0;
    if (t < RSC && j < PDW) {
        // exclusive chunk-prefix of Pdst (u8-packed, carry-free)
#pragma unroll 8
        for (int c = 0; c < NB; ++c) {
            unsigned int v = Pdst[(size_t)c * PDW + j];
            Pdst[(size_t)c * PDW + j] = run;
            run += v;
        }
        n0 = run & 0xff; n1 = (run >> 8) & 0xff;
        n2 = (run >> 16) & 0xff; n3 = (run >> 24) & 0xff;
        tot = n0 + n1 + n2 + n3;
        *(float4*)&norm_dst[4 * j] = make_float4(
            rsqrtf(fmaxf((float)n0, 1.0f)), rsqrtf(fmaxf((float)n1, 1.0f)),
            rsqrtf(fmaxf((float)n2, 1.0f)), rsqrtf(fmaxf((float)n3, 1.0f)));
        unsigned int rs = 0;
#pragma unroll 8
        for (int c = 0; c < NB; ++c) rs += Psrc[(size_t)c * PDW + j];
        int s0 = rs & 0xff, s1 = (rs >> 8) & 0xff;
        int s2 = (rs >> 16) & 0xff, s3 = (rs >> 24) & 0xff;
        *(float4*)&norm_src[4 * j] = make_float4(
            rsqrtf(fmaxf((float)s0, 1.0f)), rsqrtf(fmaxf((float)s1, 1.0f)),
            rsqrtf(fmaxf((float)s2, 1.0f)), rsqrtf(fmaxf((float)s3, 1.0f)));
    }
    // two chunk sums: cols [0,64) -> chunk 2b, [64,128) -> chunk 2b+1
    sm[t] = (t < RSC) ? tot : 0;
    __syncthreads();
    for (int off = 32; off > 0; off >>= 1) {
        if ((t & 63) < off) sm[t] += sm[t + off];
        __syncthreads();
    }
    if (t == 0)  atomicExch(&chunk_sums[2 * b], sm[0]);
    if (t == 64) atomicExch(&chunk_sums[2 * b + 1], sm[64]);
    __threadfence();
    __syncthreads();
    if (t == 0) atomicAdd(&sync[0], 1);
    // block 0 scans the 196 chunk sums once everyone reported
    if (b == 0) {
        if (t == 0) {
            while (atomicAdd(&sync[0], 0) < RSB) __builtin_amdgcn_s_sleep(8);
        }
        __syncthreads();
        __threadfence();
        int v = (t < 2 * RSB) ? atomicAdd(&chunk_sums[t], 0) : 0;
        sm[t] = v;
        __syncthreads();
        for (int off = 1; off < 256; off <<= 1) {
            int u = (t >= off) ? sm[t - off] : 0;
            __syncthreads();
            sm[t] += u;
            __syncthreads();
        }
        if (t < 2 * RSB) atomicExch(&chunk_base[t], sm[t] - v);  // exclusive
        __threadfence();
        __syncthreads();
        if (t == 0) {
            offsets[N_NODES] = N_EDGES;
            atomicExch(&sync[1], 1);
        }
    }
    // all blocks: wait for bases, then per-node offsets for their 512 nodes
    if (t == 0) {
        while (atomicAdd(&sync[1], 0) == 0) __builtin_amdgcn_s_sleep(8);
    }
    __syncthreads();
    __threadfence();
    if (t == 0) sm[0] = atomicAdd(&chunk_base[2 * b], 0);
    __syncthreads();
    const int E = sm[0];
    __syncthreads();
    sm[t] = (t < RSC) ? tot : 0;                     // 128-thread scan
    __syncthreads();
    for (int off = 1; off < 256; off <<= 1) {
        int u = (t >= off) ? sm[t - off] : 0;
        __syncthreads();
        sm[t] += u;
        __syncthreads();
    }
    if (t < RSC && j < PDW) {
        const int base0 = E + sm[t] - tot;           // exclusive within block
        *(int4*)&offsets[4 * j] = make_int4(base0, base0 + n0,
                                            base0 + n0 + n1,
                                            base0 + n0 + n1 + n2);
    }
}

// ---------------------------------------------------------------------------
// fill: one FULL-RANGE cursor table per chunk (50 KB LDS) — every edge of
// the chunk processed exactly once, all lanes active.
__global__ __launch_bounds__(512) void fill_kernel(const int* __restrict__ src,
        const int* __restrict__ dst, const int* __restrict__ offsets,
        const unsigned int* __restrict__ Pdst, int* __restrict__ csr_src) {
    __shared__ __align__(16) unsigned int cur[PDW];  // 50 KB
    const int t = threadIdx.x;
    const int chunk = blockIdx.x;
    uint2* c2 = (uint2*)cur;
    for (int j = t; j < PDW / 2; j += 512) c2[j] = make_uint2(0u, 0u);
    __syncthreads();
    const unsigned int* base = Pdst + (size_t)chunk * PDW;
    const int e0 = chunk * CHUNK;
    const int2* d2p = (const int2*)(dst + e0);       // 8B-aligned
    const int2* s2p = (const int2*)(src + e0);
    for (int k = t; k < CHUNK / 2; k += 512) {
        int2 d2 = d2p[k];
        int2 s2 = s2p[k];
        {
            const int d = d2.x;
            const int sh = (d & 3) * 8;
            const unsigned int bw = base[d >> 2];
            const int off = offsets[d];
            unsigned int old = atomicAdd(&cur[d >> 2], 1u << sh);
            csr_src[off + (int)((bw >> sh) & 0xffu) + (int)((old >> sh) & 0xffu)] = s2.x;
        }
        {
            const int d = d2.y;
            const int sh = (d & 3) * 8;
            const unsigned int bw = base[d >> 2];
            const int off = offsets[d];
            unsigned int old = atomicAdd(&cur[d >> 2], 1u << sh);
            csr_src[off + (int)((bw >> sh) & 0xffu) + (int)((old >> sh) & 0xffu)] = s2.y;
        }
    }
}

// ---------------------------------------------------------------------------
// gather1+gemm2 fused: 16 rows/block, 8 warps (each gathers 2 rows).
// Per row: Hrelu = fp16(relu((sum H1h[s,:]*ns)*nd + b1)*ns) -> LDS A-tile.
// Then warps 0..2 run the 16x48 gemm2 via MFMA (hi/lo W2) -> H2h direct.
__global__ __launch_bounds__(512) void gather1_gemm2_kernel(
        const __half* __restrict__ H1h, const int* __restrict__ offsets,
        const int* __restrict__ csr_src, const float* __restrict__ b1,
        const float* __restrict__ norm_src, const float* __restrict__ norm_dst,
        const __half* __restrict__ W2Th, const __half* __restrict__ W2Tl,
        __half* __restrict__ H2h) {
    __shared__ __align__(16) __half As[16][136];     // pad 136: 2-way banks only
    const int t = threadIdx.x;
    const int lane = t & 63;
    const int w = t >> 6;                            // warp 0..7
    const int q = lane >> 4;                         // edge slot 0..3
    const int fl = lane & 15;                        // features 8*fl..8*fl+7
    const int row0 = blockIdx.x * 16;
    for (int rr = 0; rr < 2; ++rr) {
        const int lr = 2 * w + rr;
        const int row = row0 + lr;
        const int beg = offsets[row], end = offsets[row + 1];
        float a0 = 0.f, a1 = 0.f, a2 = 0.f, a3 = 0.f;
        float a4 = 0.f, a5 = 0.f, a6 = 0.f, a7 = 0.f;
        for (int base = beg; base < end; base += 64) {
            int idx = 0;
            float nsv = 0.f;
            if (base + lane < end) {
                idx = csr_src[base + lane];
                nsv = norm_src[idx];
            }
            const int cnt = min(end - base, 64);
            for (int j = 0; j < cnt; j += 16) {
                int e0 = j + q, e1 = j + 4 + q, e2 = j + 8 + q, e3 = j + 12 + q;
                int s0 = __shfl(idx, e0);  float n0 = __shfl(nsv, e0);
                int s1 = __shfl(idx, e1);  float n1 = __shfl(nsv, e1);
                int s2 = __shfl(idx, e2);  float n2 = __shfl(nsv, e2);
                int s3 = __shfl(idx, e3);  float n3 = __shfl(nsv, e3);
                h2x4 v0 = *(const h2x4*)&H1h[(size_t)s0 * HID + 8 * fl];
                h2x4 v1 = *(const h2x4*)&H1h[(size_t)s1 * HID + 8 * fl];
                h2x4 v2 = *(const h2x4*)&H1h[(size_t)s2 * HID + 8 * fl];
                h2x4 v3 = *(const h2x4*)&H1h[(size_t)s3 * HID + 8 * fl];
                float2 f;
                f = __half22float2(v0.a); a0 = fmaf(f.x, n0, a0); a1 = fmaf(f.y, n0, a1);
                f = __half22float2(v0.b); a2 = fmaf(f.x, n0, a2); a3 = fmaf(f.y, n0, a3);
                f = __half22float2(v0.c); a4 = fmaf(f.x, n0, a4); a5 = fmaf(f.y, n0, a5);
                f = __half22float2(v0.d); a6 = fmaf(f.x, n0, a6); a7 = fmaf(f.y, n0, a7);
                f = __half22float2(v1.a); a0 = fmaf(f.x, n1, a0); a1 = fmaf(f.y, n1, a1);
                f = __half22float2(v1.b); a2 = fmaf(f.x, n1, a2); a3 = fmaf(f.y, n1, a3);
                f = __half22float2(v1.c); a4 = fmaf(f.x, n1, a4); a5 = fmaf(f.y, n1, a5);
                f = __half22float2(v1.d); a6 = fmaf(f.x, n1, a6); a7 = fmaf(f.y, n1, a7);
                f = __half22float2(v2.a); a0 = fmaf(f.x, n2, a0); a1 = fmaf(f.y, n2, a1);
                f = __half22float2(v2.b); a2 = fmaf(f.x, n2, a2); a3 = fmaf(f.y, n2, a3);
                f = __half22float2(v2.c); a4 = fmaf(f.x, n2, a4); a5 = fmaf(f.y, n2, a5);
                f = __half22float2(v2.d); a6 = fmaf(f.x, n2, a6); a7 = fmaf(f.y, n2, a7);
                f = __half22float2(v3.a); a0 = fmaf(f.x, n3, a0); a1 = fmaf(f.y, n3, a1);
                f = __half22float2(v3.b); a2 = fmaf(f.x, n3, a2); a3 = fmaf(f.y, n3, a3);
                f = __half22float2(v3.c); a4 = fmaf(f.x, n3, a4); a5 = fmaf(f.y, n3, a5);
                f = __half22float2(v3.d); a6 = fmaf(f.x, n3, a6); a7 = fmaf(f.y, n3, a7);
            }
        }
        a0 += __shfl_xor(a0, 16); a1 += __shfl_xor(a1, 16);
        a2 += __shfl_xor(a2, 16); a3 += __shfl_xor(a3, 16);
        a4 += __shfl_xor(a4, 16); a5 += __shfl_xor(a5, 16);
        a6 += __shfl_xor(a6, 16); a7 += __shfl_xor(a7, 16);
        a0 += __shfl_xor(a0, 32); a1 += __shfl_xor(a1, 32);
        a2 += __shfl_xor(a2, 32); a3 += __shfl_xor(a3, 32);
        a4 += __shfl_xor(a4, 32); a5 += __shfl_xor(a5, 32);
        a6 += __shfl_xor(a6, 32); a7 += __shfl_xor(a7, 32);
        if (lane < 16) {
            float nd = norm_dst[row], ns = norm_src[row];
            float4 bA = *(const float4*)&b1[8 * fl];
            float4 bB = *(const float4*)&b1[8 * fl + 4];
            float o0 = fmaxf(fmaf(a0, nd, bA.x), 0.f) * ns;
            float o1 = fmaxf(fmaf(a1, nd, bA.y), 0.f) * ns;
            float o2 = fmaxf(fmaf(a2, nd, bA.z), 0.f) * ns;
            float o3 = fmaxf(fmaf(a3, nd, bA.w), 0.f) * ns;
            float o4 = fmaxf(fmaf(a4, nd, bB.x), 0.f) * ns;
            float o5 = fmaxf(fmaf(a5, nd, bB.y), 0.f) * ns;
            float o6 = fmaxf(fmaf(a6, nd, bB.z), 0.f) * ns;
            float o7 = fmaxf(fmaf(a7, nd, bB.w), 0.f) * ns;
            h2x4 p = {__floats2half2_rn(o0, o1), __floats2half2_rn(o2, o3),
                      __floats2half2_rn(o4, o5), __floats2half2_rn(o6, o7)};
            *(h2x4*)&As[lr][8 * fl] = p;
        }
    }
    __syncthreads();
    // gemm2 epilogue: warps 0..2 each own one 16-col tile of W2 (48 cols)
    if (w < 3) {
        const int r16 = lane & 15;
        const int kg = lane >> 4;
        f32x4 acc = {};
#pragma unroll
        for (int s = 0; s < 4; ++s) {
            const int k0 = 32 * s + 8 * kg;
            const f16x8 a = *(const f16x8*)&As[r16][k0];
            const f16x8 bh = *(const f16x8*)&W2Th[(16 * w + r16) * HID + k0];
            const f16x8 bl = *(const f16x8*)&W2Tl[(16 * w + r16) * HID + k0];
            acc = __builtin_amdgcn_mfma_f32_16x16x32_f16(a, bh, acc, 0, 0, 0);
            acc = __builtin_amdgcn_mfma_f32_16x16x32_f16(a, bl, acc, 0, 0, 0);
        }
#pragma unroll
        for (int jj = 0; jj < 4; ++jj)
            H2h[(size_t)(row0 + 4 * kg + jj) * H2S + 16 * w + r16] =
                __float2half_rn(acc[jj]);
    }
}

// --- gather2: out[row,c] = (sum H2h[s,c])*nd + b2[c]; weight-masked tail ---
__global__ __launch_bounds__(256) void gather2_kernel(const __half* __restrict__ H2h,
        const int* __restrict__ offsets, const int* __restrict__ csr_src,
        const float* __restrict__ b2, const float* __restrict__ norm_dst,
        float* __restrict__ out) {
    const int lane = threadIdx.x & 63;
    const int row = blockIdx.x * 4 + (threadIdx.x >> 6);
    const int beg = offsets[row], end = offsets[row + 1];
    const int cl = min(lane, H2S - 1);
    float acc = 0.f;
    for (int base = beg; base < end; base += 64) {
        int idx = 0;
        float wv = 0.f;
        if (base + lane < end) {
            idx = csr_src[base + lane];
            wv = 1.f;
        }
        const int cnt = min(end - base, 64);
        for (int j = 0; j < cnt; j += 4) {
            int s0 = __shfl(idx, j);     float w0 = __shfl(wv, j);
            int s1 = __shfl(idx, j + 1); float w1 = __shfl(wv, j + 1);
            int s2 = __shfl(idx, j + 2); float w2 = __shfl(wv, j + 2);
            int s3 = __shfl(idx, j + 3); float w3 = __shfl(wv, j + 3);
            float f0 = __half2float(H2h[(size_t)s0 * H2S + cl]);
            float f1 = __half2float(H2h[(size_t)s1 * H2S + cl]);
            float f2 = __half2float(H2h[(size_t)s2 * H2S + cl]);
            float f3 = __half2float(H2h[(size_t)s3 * H2S + cl]);
            acc = fmaf(f0, w0, acc);
            acc = fmaf(f1, w1, acc);
            acc = fmaf(f2, w2, acc);
            acc = fmaf(f3, w3, acc);
        }
    }
    if (lane < NCLS) out[(size_t)row * NCLS + lane] = acc * norm_dst[row] + b2[lane];
}

// ---------------------------------------------------------------------------
extern "C" void kernel_launch(void* const* d_in, const int* in_sizes, int n_in,
                              void* d_out, int out_size, void* d_ws, size_t ws_size,
                              hipStream_t stream) {
    const float* X  = (const float*)d_in[0];
    const int*   ei = (const int*)d_in[1];
    const float* W1 = (const float*)d_in[2];
    const float* b1 = (const float*)d_in[3];
    const float* W2 = (const float*)d_in[4];
    const float* b2 = (const float*)d_in[5];
    float* out = (float*)d_out;

    const int* src = ei;
    const int* dst = ei + N_EDGES;

    char* w = (char*)d_ws;
    auto alloc = [&](size_t bytes) {
        char* p = w;
        w += (bytes + 255) & ~(size_t)255;
        return p;
    };
    float*  norm_src   = (float*)alloc(N_NODES * 4);
    float*  norm_dst   = (float*)alloc(N_NODES * 4);
    int*    offsets    = (int*)alloc((N_NODES + 1) * 4);
    int*    csr_src    = (int*)alloc((size_t)N_EDGES * 4);
    int*    chunk_sums = (int*)alloc(2 * RSB * 4);
    int*    chunk_base = (int*)alloc(2 * RSB * 4);
    int*    syncw      = (int*)alloc(2 * 4);
    __half* W1Th       = (__half*)alloc((size_t)IN_F * HID * 2);
    __half* W1Tl       = (__half*)alloc((size_t)IN_F * HID * 2);
    __half* W2Th       = (__half*)alloc((size_t)64 * HID * 2);
    __half* W2Tl       = (__half*)alloc((size_t)64 * HID * 2);
    __half* H1h        = (__half*)alloc((size_t)N_NODES * HID * 2);   // 12.8 MB
    __half* H2h        = (__half*)alloc((size_t)N_NODES * H2S * 2);   //  4.8 MB
    unsigned int* Pdst = (unsigned int*)alloc((size_t)NB * PDW * 4);  //  6.4 MB
    unsigned int* Psrc = (unsigned int*)alloc((size_t)NB * PDW * 4);  //  6.4 MB

    const int g1_blocks = (N_NODES + G1ROWS - 1) / G1ROWS;            // 196
    prep_kernel<<<49, 256, 0, stream>>>(W1, W2, W1Th, W1Tl, W2Th, W2Tl, syncw);
    hist_gemm1_kernel<<<2 * NB + g1_blocks, 512, 0, stream>>>(ei, Pdst, Psrc,
                                                              X, W1Th, W1Tl, H1h);
    reduce_scan_kernel<<<RSB, 256, 0, stream>>>(Pdst, Psrc, norm_src, norm_dst,
                                                offsets, chunk_sums, chunk_base,
                                                syncw);
    fill_kernel<<<NB, 512, 0, stream>>>(src, dst, offsets, Pdst, csr_src);
    gather1_gemm2_kernel<<<N_NODES / 16, 512, 0, stream>>>(H1h, offsets, csr_src,
                                                           b1, norm_src, norm_dst,
                                                           W2Th, W2Tl, H2h);
    gather2_kernel<<<N_NODES / 4, 256, 0, stream>>>(H2h, offsets, csr_src, b2,
                                                    norm_dst, out);
}

// Round 7
// 202.810 us; speedup vs baseline: 2.3772x; 1.0920x over previous
//
#include <hip/hip_runtime.h>
#include <hip/hip_fp16.h>

#define N_NODES 50000
#define N_EDGES 800000
#define IN_F 128
#define HID 128
#define NCLS 47
#define H2S 48          // H2 row stride (halfs)
#define W2C 64          // padded W2 col count (fp16 transposed)
#define NCH 196         // node chunks (256 nodes each)
#define NB 128          // dst edge chunks
#define CHUNK 6250      // edges per dst chunk (NB*CHUNK == N_EDGES)
#define SB 16           // src edge chunks (coarse: totals only)
#define SCHUNK 50000    // edges per src chunk (SB*SCHUNK == N_EDGES)
#define PDW 12500       // dwords per full histogram (u8 x 4 nodes) = 50 KB LDS
#define G1B 196         // gemm1 blocks
#define G1ROWS 256      // rows per gemm1 block (8 waves x 32 rows)
#define G2ROWS 128      // rows per gemm2 block (4 waves x 32 rows)

// u8 packing safety: per-dst-chunk per-node counts <= ~8; per-src-chunk
// (50K edges, Poisson mean 1) <= ~14 — all << 255, carry-free u8 adds.

typedef _Float16 f16x8 __attribute__((ext_vector_type(8)));
typedef float f32x4 __attribute__((ext_vector_type(4)));

struct __align__(8)  h2x2 { __half2 a, b; };
struct __align__(16) h2x4 { __half2 a, b, c, d; };

// ---------------------------------------------------------------------------
// prep: fp16 hi/lo transposed weight splits (feeds gemm1/gemm2 in LATER
// dispatches — must stay a separate kernel, gemm1 is co-scheduled with hist).
__global__ __launch_bounds__(256) void prep_kernel(const float* __restrict__ W1,
                                                   const float* __restrict__ W2,
                                                   __half* __restrict__ W1Th,
                                                   __half* __restrict__ W1Tl,
                                                   __half* __restrict__ W2Th,
                                                   __half* __restrict__ W2Tl) {
    const int b = blockIdx.x, t = threadIdx.x;
    if (b < 32) {
        // W1 -> transposed, fp16 hi/lo: W1T*[c*IN_F + k]
        const int i0 = b * 512;
        for (int i2 = i0 + t; i2 < i0 + 512; i2 += 256) {
            int cc = i2 >> 7, k = i2 & 127;
            float w = W1[k * HID + cc];
            __half hv = __float2half_rn(w);
            W1Th[i2] = hv;
            W1Tl[i2] = __float2half_rn(w - __half2float(hv));
        }
    } else {
        // W2 -> padded(64), transposed, fp16 hi/lo: W2T*[c*HID + k]
        const int i0 = (b - 32) * 512;                 // 16 x 512 = 8192
        for (int i2 = i0 + t; i2 < i0 + 512; i2 += 256) {
            int cc = i2 >> 7, k = i2 & 127;
            float w = (cc < NCLS) ? W2[k * NCLS + cc] : 0.f;
            __half hv = __float2half_rn(w);
            W2Th[i2] = hv;
            W2Tl[i2] = __float2half_rn(w - __half2float(hv));
        }
    }
}

// ---------------------------------------------------------------------------
// gemm1 + hist mega. Blocks [0,G1B): gemm1 MFMA (long poles, start first).
// Blocks [G1B, G1B+NB): full-range u8 dst histograms (one per dst chunk).
// Blocks [G1B+NB, G1B+NB+SB): coarse full-range src histograms (totals only).
__global__ __launch_bounds__(512) void hist_gemm1_kernel(const int* __restrict__ ei,
        unsigned int* __restrict__ Pdst, unsigned int* __restrict__ Psrc,
        const float* __restrict__ X, const __half* __restrict__ W1Th,
        const __half* __restrict__ W1Tl, __half* __restrict__ H1h) {
    __shared__ unsigned int h[PDW];              // 50 KB u8-packed counters
    const int t = threadIdx.x;
    if (blockIdx.x >= G1B) {
        const int hb = blockIdx.x - G1B;
        const bool is_src = hb >= NB;
        const int chunk = is_src ? (hb - NB) : hb;
        const int* ids = is_src ? ei : ei + N_EDGES;
        const int cnt = is_src ? SCHUNK : CHUNK;
        uint2* h2 = (uint2*)h;
        for (int j = t; j < PDW / 2; j += 512) h2[j] = make_uint2(0u, 0u);
        __syncthreads();
        const int e0 = chunk * cnt;
        const int2* e2p = (const int2*)(ids + e0);   // 8B-aligned
        for (int k = t; k < cnt / 2; k += 512) {
            int2 v2 = e2p[k];
            atomicAdd(&h[v2.x >> 2], 1u << ((v2.x & 3) * 8));
            atomicAdd(&h[v2.y >> 2], 1u << ((v2.y & 3) * 8));
        }
        __syncthreads();
        unsigned int* P = (is_src ? Psrc : Pdst) + (size_t)chunk * PDW;
        uint2* P2 = (uint2*)P;
        for (int j = t; j < PDW / 2; j += 512) P2[j] = h2[j];
    } else {
        // ---- gemm1: MFMA 16x16x32_f16, 256 rows/block, 8 waves ----
        // A frag: row=lane&15, k=8*(lane>>4)+j; C: col=lane&15, row=4*(lane>>4)+reg
        const int lane = t & 63;
        const int wv = t >> 6;
        const int r16 = lane & 15;
        const int kg = lane >> 4;
        const int row0 = blockIdx.x * G1ROWS + wv * 32;
        f32x4 acc[2][8] = {};
#pragma unroll
        for (int s = 0; s < 4; ++s) {                // K steps of 32
            const int k0 = 32 * s + 8 * kg;
            f16x8 ah[2], al[2];
#pragma unroll
            for (int rt = 0; rt < 2; ++rt) {
                int row = row0 + rt * 16 + r16;
                int rc = row < N_NODES ? row : N_NODES - 1;
                const float4 x0 = *(const float4*)&X[(size_t)rc * IN_F + k0];
                const float4 x1 = *(const float4*)&X[(size_t)rc * IN_F + k0 + 4];
                const float xv[8] = {x0.x, x0.y, x0.z, x0.w,
                                     x1.x, x1.y, x1.z, x1.w};
#pragma unroll
                for (int j = 0; j < 8; ++j) {
                    _Float16 hv = (_Float16)xv[j];
                    ah[rt][j] = hv;
                    al[rt][j] = (_Float16)(xv[j] - (float)hv);
                }
            }
#pragma unroll
            for (int tt = 0; tt < 8; ++tt) {         // 8 col tiles of 16
                const f16x8 bh = *(const f16x8*)&W1Th[(16 * tt + r16) * IN_F + k0];
                const f16x8 bl = *(const f16x8*)&W1Tl[(16 * tt + r16) * IN_F + k0];
#pragma unroll
                for (int rt = 0; rt < 2; ++rt) {
                    acc[rt][tt] = __builtin_amdgcn_mfma_f32_16x16x32_f16(
                        ah[rt], bh, acc[rt][tt], 0, 0, 0);
                    acc[rt][tt] = __builtin_amdgcn_mfma_f32_16x16x32_f16(
                        al[rt], bh, acc[rt][tt], 0, 0, 0);
                    acc[rt][tt] = __builtin_amdgcn_mfma_f32_16x16x32_f16(
                        ah[rt], bl, acc[rt][tt], 0, 0, 0);
                }
            }
        }
#pragma unroll
        for (int rt = 0; rt < 2; ++rt)
#pragma unroll
            for (int j = 0; j < 4; ++j) {
                const int row = row0 + rt * 16 + 4 * kg + j;
                if (row < N_NODES) {
#pragma unroll
                    for (int tt = 0; tt < 8; ++tt)
                        H1h[(size_t)row * HID + 16 * tt + r16] =
                            __float2half_rn(acc[rt][tt][j]);
                }
            }
    }
}

// reduce: packed-u8 exclusive chunk-scan of Pdst (128), src totals from
// Psrc (16 coarse), norms, per-256-node chunk sums.
__global__ __launch_bounds__(256) void reduce_kernel(unsigned int* __restrict__ Pdst,
                                                     const unsigned int* __restrict__ Psrc,
                                                     int* __restrict__ cnt_in,
                                                     float* __restrict__ norm_src,
                                                     float* __restrict__ norm_dst,
                                                     int* __restrict__ chunk_sums) {
    __shared__ int sm[256];
    const int t = threadIdx.x;
    const int j = blockIdx.x * 256 + t;
    int tot = 0;
    if (j < PDW) {
        unsigned int run = 0;
#pragma unroll 8
        for (int b = 0; b < NB; ++b) {
            unsigned int v = Pdst[(size_t)b * PDW + j];
            Pdst[(size_t)b * PDW + j] = run;         // exclusive prefix (packed u8)
            run += v;
        }
        int n0 = run & 0xff, n1 = (run >> 8) & 0xff;
        int n2 = (run >> 16) & 0xff, n3 = (run >> 24) & 0xff;
        *(int4*)&cnt_in[4 * j] = make_int4(n0, n1, n2, n3);
        *(float4*)&norm_dst[4 * j] = make_float4(
            rsqrtf(fmaxf((float)n0, 1.0f)), rsqrtf(fmaxf((float)n1, 1.0f)),
            rsqrtf(fmaxf((float)n2, 1.0f)), rsqrtf(fmaxf((float)n3, 1.0f)));
        tot = n0 + n1 + n2 + n3;
        unsigned int rs = 0;
#pragma unroll
        for (int b = 0; b < SB; ++b) rs += Psrc[(size_t)b * PDW + j];
        int s0 = rs & 0xff, s1 = (rs >> 8) & 0xff;
        int s2 = (rs >> 16) & 0xff, s3 = (rs >> 24) & 0xff;
        *(float4*)&norm_src[4 * j] = make_float4(
            rsqrtf(fmaxf((float)s0, 1.0f)), rsqrtf(fmaxf((float)s1, 1.0f)),
            rsqrtf(fmaxf((float)s2, 1.0f)), rsqrtf(fmaxf((float)s3, 1.0f)));
    }
    sm[t] = tot;
    __syncthreads();
    const int g = t & 63;                            // 64 threads = 256 nodes
    for (int off = 32; off > 0; off >>= 1) {
        if (g < off) sm[t] += sm[t + off];
        __syncthreads();
    }
    if (g == 0) chunk_sums[blockIdx.x * 4 + (t >> 6)] = sm[t];
}

// offsets: each block recomputes the chunk base from chunk_sums then scans
// its 256 nodes.
__global__ __launch_bounds__(256) void scan3_kernel(const int* __restrict__ cnt_in,
                                                    const int* __restrict__ chunk_sums,
                                                    int* __restrict__ offsets) {
    __shared__ int sm[256];
    const int t = threadIdx.x;
    int v = (t < NCH) ? chunk_sums[t] : 0;
    sm[t] = v;
    __syncthreads();
    for (int off = 1; off < 256; off <<= 1) {
        int u = (t >= off) ? sm[t - off] : 0;
        __syncthreads();
        sm[t] += u;
        __syncthreads();
    }
    const int basev = (blockIdx.x == 0) ? 0 : sm[blockIdx.x - 1];
    __syncthreads();
    const int idx = blockIdx.x * 256 + t;
    int c = (idx < N_NODES) ? cnt_in[idx] : 0;
    sm[t] = c;
    __syncthreads();
    for (int off = 1; off < 256; off <<= 1) {
        int u = (t >= off) ? sm[t - off] : 0;
        __syncthreads();
        sm[t] += u;
        __syncthreads();
    }
    if (idx < N_NODES) offsets[idx] = basev + sm[t] - c;
    if (blockIdx.x == 0 && t == 0) offsets[N_NODES] = N_EDGES;
}

// fill: one FULL-RANGE cursor table per dst chunk (50 KB LDS) — every edge
// of the chunk processed exactly once, all lanes active.
__global__ __launch_bounds__(512) void fill_kernel(const int* __restrict__ src,
        const int* __restrict__ dst, const int* __restrict__ offsets,
        const unsigned int* __restrict__ Pdst, int* __restrict__ csr_src) {
    __shared__ __align__(16) unsigned int cur[PDW];  // 50 KB
    const int t = threadIdx.x;
    const int chunk = blockIdx.x;
    uint2* c2 = (uint2*)cur;
    for (int j = t; j < PDW / 2; j += 512) c2[j] = make_uint2(0u, 0u);
    __syncthreads();
    const unsigned int* base = Pdst + (size_t)chunk * PDW;
    const int e0 = chunk * CHUNK;
    const int2* d2p = (const int2*)(dst + e0);       // 8B-aligned
    const int2* s2p = (const int2*)(src + e0);
    for (int k = t; k < CHUNK / 2; k += 512) {
        int2 d2 = d2p[k];
        int2 s2 = s2p[k];
        {
            const int d = d2.x;
            const int sh = (d & 3) * 8;
            const unsigned int bw = base[d >> 2];    // independent of atomic
            const int off = offsets[d];              // independent of atomic
            unsigned int old = atomicAdd(&cur[d >> 2], 1u << sh);
            csr_src[off + (int)((bw >> sh) & 0xffu) + (int)((old >> sh) & 0xffu)] = s2.x;
        }
        {
            const int d = d2.y;
            const int sh = (d & 3) * 8;
            const unsigned int bw = base[d >> 2];
            const int off = offsets[d];
            unsigned int old = atomicAdd(&cur[d >> 2], 1u << sh);
            csr_src[off + (int)((bw >> sh) & 0xffu) + (int)((old >> sh) & 0xffu)] = s2.y;
        }
    }
}

// --- gather1: Hrelu16[row,:] = fp16(relu((sum ns[s]*H1h[s,:])*nd + b1)*ns) -
__global__ __launch_bounds__(256) void gather1_kernel(const __half* __restrict__ H1h,
        const int* __restrict__ offsets, const int* __restrict__ csr_src,
        const float* __restrict__ b1, const float* __restrict__ norm_src,
        const float* __restrict__ norm_dst, __half* __restrict__ Hrelu16) {
    const int lane = threadIdx.x & 63;
    const int q = lane >> 4;              // edge slot 0..3
    const int fl = lane & 15;             // features 8*fl .. 8*fl+7
    const int row = blockIdx.x * 4 + (threadIdx.x >> 6);
    const int beg = offsets[row], end = offsets[row + 1];
    float a0 = 0.f, a1 = 0.f, a2 = 0.f, a3 = 0.f;
    float a4 = 0.f, a5 = 0.f, a6 = 0.f, a7 = 0.f;
    for (int base = beg; base < end; base += 64) {
        int idx = 0;
        float nsv = 0.f;
        if (base + lane < end) {
            idx = csr_src[base + lane];
            nsv = norm_src[idx];
        }
        const int cnt = min(end - base, 64);
        for (int j = 0; j < cnt; j += 16) {
            int e0 = j + q, e1 = j + 4 + q, e2 = j + 8 + q, e3 = j + 12 + q;
            int s0 = __shfl(idx, e0);  float n0 = __shfl(nsv, e0);
            int s1 = __shfl(idx, e1);  float n1 = __shfl(nsv, e1);
            int s2 = __shfl(idx, e2);  float n2 = __shfl(nsv, e2);
            int s3 = __shfl(idx, e3);  float n3 = __shfl(nsv, e3);
            h2x4 v0 = *(const h2x4*)&H1h[(size_t)s0 * HID + 8 * fl];
            h2x4 v1 = *(const h2x4*)&H1h[(size_t)s1 * HID + 8 * fl];
            h2x4 v2 = *(const h2x4*)&H1h[(size_t)s2 * HID + 8 * fl];
            h2x4 v3 = *(const h2x4*)&H1h[(size_t)s3 * HID + 8 * fl];
            float2 f;
            f = __half22float2(v0.a); a0 = fmaf(f.x, n0, a0); a1 = fmaf(f.y, n0, a1);
            f = __half22float2(v0.b); a2 = fmaf(f.x, n0, a2); a3 = fmaf(f.y, n0, a3);
            f = __half22float2(v0.c); a4 = fmaf(f.x, n0, a4); a5 = fmaf(f.y, n0, a5);
            f = __half22float2(v0.d); a6 = fmaf(f.x, n0, a6); a7 = fmaf(f.y, n0, a7);
            f = __half22float2(v1.a); a0 = fmaf(f.x, n1, a0); a1 = fmaf(f.y, n1, a1);
            f = __half22float2(v1.b); a2 = fmaf(f.x, n1, a2); a3 = fmaf(f.y, n1, a3);
            f = __half22float2(v1.c); a4 = fmaf(f.x, n1, a4); a5 = fmaf(f.y, n1, a5);
            f = __half22float2(v1.d); a6 = fmaf(f.x, n1, a6); a7 = fmaf(f.y, n1, a7);
            f = __half22float2(v2.a); a0 = fmaf(f.x, n2, a0); a1 = fmaf(f.y, n2, a1);
            f = __half22float2(v2.b); a2 = fmaf(f.x, n2, a2); a3 = fmaf(f.y, n2, a3);
            f = __half22float2(v2.c); a4 = fmaf(f.x, n2, a4); a5 = fmaf(f.y, n2, a5);
            f = __half22float2(v2.d); a6 = fmaf(f.x, n2, a6); a7 = fmaf(f.y, n2, a7);
            f = __half22float2(v3.a); a0 = fmaf(f.x, n3, a0); a1 = fmaf(f.y, n3, a1);
            f = __half22float2(v3.b); a2 = fmaf(f.x, n3, a2); a3 = fmaf(f.y, n3, a3);
            f = __half22float2(v3.c); a4 = fmaf(f.x, n3, a4); a5 = fmaf(f.y, n3, a5);
            f = __half22float2(v3.d); a6 = fmaf(f.x, n3, a6); a7 = fmaf(f.y, n3, a7);
        }
    }
    a0 += __shfl_xor(a0, 16); a1 += __shfl_xor(a1, 16);
    a2 += __shfl_xor(a2, 16); a3 += __shfl_xor(a3, 16);
    a4 += __shfl_xor(a4, 16); a5 += __shfl_xor(a5, 16);
    a6 += __shfl_xor(a6, 16); a7 += __shfl_xor(a7, 16);
    a0 += __shfl_xor(a0, 32); a1 += __shfl_xor(a1, 32);
    a2 += __shfl_xor(a2, 32); a3 += __shfl_xor(a3, 32);
    a4 += __shfl_xor(a4, 32); a5 += __shfl_xor(a5, 32);
    a6 += __shfl_xor(a6, 32); a7 += __shfl_xor(a7, 32);
    if (lane < 16) {
        float nd = norm_dst[row], ns = norm_src[row];
        float4 bA = *(const float4*)&b1[8 * fl];
        float4 bB = *(const float4*)&b1[8 * fl + 4];
        float o0 = fmaxf(fmaf(a0, nd, bA.x), 0.f) * ns;
        float o1 = fmaxf(fmaf(a1, nd, bA.y), 0.f) * ns;
        float o2 = fmaxf(fmaf(a2, nd, bA.z), 0.f) * ns;
        float o3 = fmaxf(fmaf(a3, nd, bA.w), 0.f) * ns;
        float o4 = fmaxf(fmaf(a4, nd, bB.x), 0.f) * ns;
        float o5 = fmaxf(fmaf(a5, nd, bB.y), 0.f) * ns;
        float o6 = fmaxf(fmaf(a6, nd, bB.z), 0.f) * ns;
        float o7 = fmaxf(fmaf(a7, nd, bB.w), 0.f) * ns;
        h2x4 p = {__floats2half2_rn(o0, o1), __floats2half2_rn(o2, o3),
                  __floats2half2_rn(o4, o5), __floats2half2_rn(o6, o7)};
        *(h2x4*)&Hrelu16[(size_t)row * HID + 8 * fl] = p;
    }
}

// --- gemm2: H2h[row, 0..47] = fp16( Hrelu16[row,:] @ W2 ), MFMA, no LDS ---
__global__ __launch_bounds__(256) void gemm2_kernel(const __half* __restrict__ Hrelu16,
                                                    const __half* __restrict__ W2Th,
                                                    const __half* __restrict__ W2Tl,
                                                    __half* __restrict__ H2h) {
    const int lane = threadIdx.x & 63;
    const int wv = threadIdx.x >> 6;
    const int r16 = lane & 15;
    const int kg = lane >> 4;
    const int row0 = blockIdx.x * G2ROWS + wv * 32;
    f32x4 acc[2][3] = {};                 // 3 col tiles = 48 cols exactly
#pragma unroll
    for (int s = 0; s < 4; ++s) {
        const int k0 = 32 * s + 8 * kg;
        f16x8 a[2];
#pragma unroll
        for (int rt = 0; rt < 2; ++rt) {
            int row = row0 + rt * 16 + r16;
            int rc = row < N_NODES ? row : N_NODES - 1;
            a[rt] = *(const f16x8*)&Hrelu16[(size_t)rc * HID + k0];
        }
#pragma unroll
        for (int tt = 0; tt < 3; ++tt) {
            const f16x8 bh = *(const f16x8*)&W2Th[(16 * tt + r16) * HID + k0];
            const f16x8 bl = *(const f16x8*)&W2Tl[(16 * tt + r16) * HID + k0];
#pragma unroll
            for (int rt = 0; rt < 2; ++rt) {
                acc[rt][tt] = __builtin_amdgcn_mfma_f32_16x16x32_f16(
                    a[rt], bh, acc[rt][tt], 0, 0, 0);
                acc[rt][tt] = __builtin_amdgcn_mfma_f32_16x16x32_f16(
                    a[rt], bl, acc[rt][tt], 0, 0, 0);
            }
        }
    }
#pragma unroll
    for (int rt = 0; rt < 2; ++rt)
#pragma unroll
        for (int j = 0; j < 4; ++j) {
            const int row = row0 + rt * 16 + 4 * kg + j;
            if (row < N_NODES) {
#pragma unroll
                for (int tt = 0; tt < 3; ++tt)
                    H2h[(size_t)row * H2S + 16 * tt + r16] =
                        __float2half_rn(acc[rt][tt][j]);
            }
        }
}

// --- gather2: out[row,c] = (sum H2h[s,c])*nd + b2[c]; weight-masked tail ---
__global__ __launch_bounds__(256) void gather2_kernel(const __half* __restrict__ H2h,
        const int* __restrict__ offsets, const int* __restrict__ csr_src,
        const float* __restrict__ b2, const float* __restrict__ norm_dst,
        float* __restrict__ out) {
    const int lane = threadIdx.x & 63;
    const int row = blockIdx.x * 4 + (threadIdx.x >> 6);
    const int beg = offsets[row], end = offsets[row + 1];
    const int cl = min(lane, H2S - 1);
    float acc = 0.f;
    for (int base = beg; base < end; base += 64) {
        int idx = 0;
        float wv = 0.f;
        if (base + lane < end) {
            idx = csr_src[base + lane];
            wv = 1.f;
        }
        const int cnt = min(end - base, 64);
        for (int j = 0; j < cnt; j += 4) {
            int s0 = __shfl(idx, j);     float w0 = __shfl(wv, j);
            int s1 = __shfl(idx, j + 1); float w1 = __shfl(wv, j + 1);
            int s2 = __shfl(idx, j + 2); float w2 = __shfl(wv, j + 2);
            int s3 = __shfl(idx, j + 3); float w3 = __shfl(wv, j + 3);
            float f0 = __half2float(H2h[(size_t)s0 * H2S + cl]);
            float f1 = __half2float(H2h[(size_t)s1 * H2S + cl]);
            float f2 = __half2float(H2h[(size_t)s2 * H2S + cl]);
            float f3 = __half2float(H2h[(size_t)s3 * H2S + cl]);
            acc = fmaf(f0, w0, acc);
            acc = fmaf(f1, w1, acc);
            acc = fmaf(f2, w2, acc);
            acc = fmaf(f3, w3, acc);
        }
    }
    if (lane < NCLS) out[(size_t)row * NCLS + lane] = acc * norm_dst[row] + b2[lane];
}

// ---------------------------------------------------------------------------
extern "C" void kernel_launch(void* const* d_in, const int* in_sizes, int n_in,
                              void* d_out, int out_size, void* d_ws, size_t ws_size,
                              hipStream_t stream) {
    const float* X  = (const float*)d_in[0];
    const int*   ei = (const int*)d_in[1];
    const float* W1 = (const float*)d_in[2];
    const float* b1 = (const float*)d_in[3];
    const float* W2 = (const float*)d_in[4];
    const float* b2 = (const float*)d_in[5];
    float* out = (float*)d_out;

    const int* src = ei;
    const int* dst = ei + N_EDGES;

    char* w = (char*)d_ws;
    auto alloc = [&](size_t bytes) {
        char* p = w;
        w += (bytes + 255) & ~(size_t)255;
        return p;
    };
    float*  norm_src   = (float*)alloc(N_NODES * 4);
    float*  norm_dst   = (float*)alloc(N_NODES * 4);
    int*    cnt_in     = (int*)alloc(N_NODES * 4);
    int*    offsets    = (int*)alloc((N_NODES + 1) * 4);
    int*    csr_src    = (int*)alloc((size_t)N_EDGES * 4);
    int*    chunk_sums = (int*)alloc(NCH * 4);
    __half* W1Th       = (__half*)alloc((size_t)IN_F * HID * 2);
    __half* W1Tl       = (__half*)alloc((size_t)IN_F * HID * 2);
    __half* W2Th       = (__half*)alloc((size_t)W2C * HID * 2);
    __half* W2Tl       = (__half*)alloc((size_t)W2C * HID * 2);
    __half* H1h        = (__half*)alloc((size_t)N_NODES * HID * 2);   // 12.8 MB
    __half* Hrelu16    = (__half*)alloc((size_t)N_NODES * HID * 2);   // 12.8 MB
    __half* H2h        = (__half*)alloc((size_t)N_NODES * H2S * 2);   //  4.8 MB
    unsigned int* Pdst = (unsigned int*)alloc((size_t)NB * PDW * 4);  //  6.4 MB
    unsigned int* Psrc = (unsigned int*)alloc((size_t)SB * PDW * 4);  //  0.8 MB

    const int g2_blocks = (N_NODES + G2ROWS - 1) / G2ROWS;            // 391
    prep_kernel<<<48, 256, 0, stream>>>(W1, W2, W1Th, W1Tl, W2Th, W2Tl);
    hist_gemm1_kernel<<<G1B + NB + SB, 512, 0, stream>>>(ei, Pdst, Psrc,
                                                         X, W1Th, W1Tl, H1h);
    reduce_kernel<<<(PDW + 255) / 256, 256, 0, stream>>>(Pdst, Psrc, cnt_in,
                                                         norm_src, norm_dst, chunk_sums);
    scan3_kernel<<<NCH, 256, 0, stream>>>(cnt_in, chunk_sums, offsets);
    fill_kernel<<<NB, 512, 0, stream>>>(src, dst, offsets, Pdst, csr_src);
    gather1_kernel<<<N_NODES / 4, 256, 0, stream>>>(H1h, offsets, csr_src, b1,
                                                    norm_src, norm_dst, Hrelu16);
    gemm2_kernel<<<g2_blocks, 256, 0, stream>>>(Hrelu16, W2Th, W2Tl, H2h);
    gather2_kernel<<<N_NODES / 4, 256, 0, stream>>>(H2h, offsets, csr_src, b2,
                                                    norm_dst, out);
}